// Round 1
// baseline (536.601 us; speedup 1.0000x reference)
//
#include <hip/hip_runtime.h>
#include <math.h>

// ---------- problem constants ----------
#define BB   8
#define NN   4096
#define CC   768
#define HH   12
#define DD   64
#define LL   64
#define BH   96          // BB*HH
#define MM_  32768       // BB*NN
#define KQKV 768
#define NQKV 2304

typedef short bf16x8 __attribute__((ext_vector_type(8)));
typedef float f32x4  __attribute__((ext_vector_type(4)));

union U4 { unsigned long long ll; unsigned short s[4]; };

__device__ __forceinline__ unsigned short f2bf(float f) {
  union { float f; unsigned u; } v; v.f = f;
  return (unsigned short)((v.u + 0x7FFFu + ((v.u >> 16) & 1u)) >> 16);
}
__device__ __forceinline__ float bf2f(unsigned short h) {
  union { unsigned u; float f; } v; v.u = ((unsigned)h) << 16;
  return v.f;
}
__device__ __forceinline__ f32x4 fzero4() {
  f32x4 z; z[0] = 0.f; z[1] = 0.f; z[2] = 0.f; z[3] = 0.f; return z;
}
__device__ __forceinline__ void gload_lds16(const void* g, void* l) {
  __builtin_amdgcn_global_load_lds(
      (const __attribute__((address_space(1))) void*)g,
      (__attribute__((address_space(3))) void*)l, 16, 0, 0);
}

// ---------- elementwise fp32 -> bf16 ----------
__global__ void conv_bf16(const float* __restrict__ in, short* __restrict__ out, int n4) {
  int i = blockIdx.x * 256 + threadIdx.x;
  if (i >= n4) return;
  float4 v = ((const float4*)in)[i];
  U4 p; p.s[0] = f2bf(v.x); p.s[1] = f2bf(v.y); p.s[2] = f2bf(v.z); p.s[3] = f2bf(v.w);
  ((unsigned long long*)out)[i] = p.ll;
}

// ---------- transpose fp32[R][C] -> bf16[C][R] ----------
__global__ __launch_bounds__(256) void transpose_bf16(
    const float* __restrict__ in, short* __restrict__ out, int R, int C) {
  __shared__ float tile[32][33];
  int c0 = blockIdx.x * 32, r0 = blockIdx.y * 32;
  int tx = threadIdx.x & 31, ty = threadIdx.x >> 5;
  for (int i = ty; i < 32; i += 8)
    tile[i][tx] = in[(r0 + i) * C + c0 + tx];
  __syncthreads();
  for (int i = ty; i < 32; i += 8)
    out[(c0 + i) * R + r0 + tx] = (short)f2bf(tile[tx][i]);
}

// ---------- 128x128 bf16 MFMA GEMM, K=768, two epilogues ----------
// EPI 0: qkv  (A=xb,  B=wqkvT)  -> Qb (scaled 1/8), Kb, VTb (transposed V)
// EPI 1: proj (A=SVb, B=wprojT) -> fout = acc + bias + V-residual (from VTb)
template <int EPI>
__global__ __launch_bounds__(256) void gemm128(
    const short* __restrict__ A, const short* __restrict__ Bw,
    short* __restrict__ o0, short* __restrict__ o1, short* __restrict__ o2,
    const float* __restrict__ bias, float* __restrict__ fout) {
  __shared__ short Als[128 * 32];
  __shared__ short Bls[128 * 32];
  const int t = threadIdx.x;
  const int m0 = blockIdx.x * 128;
  const int n0 = blockIdx.y * 128;
  const int wave = t >> 6, lane = t & 63;
  const int wr = (wave >> 1) << 6, wc = (wave & 1) << 6;
  const int lrow = lane & 15, lk = (lane >> 4) << 3;

  f32x4 acc[4][4];
#pragma unroll
  for (int i = 0; i < 4; i++)
#pragma unroll
    for (int j = 0; j < 4; j++) acc[i][j] = fzero4();

  const int arow = t >> 2;
  const int kc8 = (t & 3) << 3;
  const short* ag = A  + (m0 + arow) * KQKV + kc8;
  const short* bg = Bw + (n0 + arow) * KQKV + kc8;
  short* alds = Als + wave * 512;
  short* blds = Bls + wave * 512;

  for (int kt = 0; kt < KQKV; kt += 32) {
    gload_lds16(ag + kt, alds);
    gload_lds16(ag + 64 * KQKV + kt, alds + 2048);
    gload_lds16(bg + kt, blds);
    gload_lds16(bg + 64 * KQKV + kt, blds + 2048);
    __syncthreads();
    bf16x8 af[4], bfr[4];
#pragma unroll
    for (int i = 0; i < 4; i++) af[i]  = *(const bf16x8*)&Als[(wr + i * 16 + lrow) * 32 + lk];
#pragma unroll
    for (int j = 0; j < 4; j++) bfr[j] = *(const bf16x8*)&Bls[(wc + j * 16 + lrow) * 32 + lk];
#pragma unroll
    for (int i = 0; i < 4; i++)
#pragma unroll
      for (int j = 0; j < 4; j++)
        acc[i][j] = __builtin_amdgcn_mfma_f32_16x16x32_bf16(af[i], bfr[j], acc[i][j], 0, 0, 0);
    __syncthreads();
  }

  if constexpr (EPI == 0) {
    const int three = n0 / 768;
    const int ccbase = n0 % 768;
#pragma unroll
    for (int jf = 0; jf < 4; jf++) {
      const int cc = ccbase + wc + jf * 16 + lrow;
      const int h = cc >> 6, d = cc & 63;
#pragma unroll
      for (int rf = 0; rf < 4; rf++) {
        const int r = m0 + wr + rf * 16 + ((lane >> 4) << 2);
        const int b = r >> 12, n = r & 4095;
        const int bh = b * HH + h;
        if (three == 0) {
#pragma unroll
          for (int i = 0; i < 4; i++)
            o0[(bh * NN + n + i) * DD + d] = (short)f2bf(acc[rf][jf][i] * 0.125f);
        } else if (three == 1) {
#pragma unroll
          for (int i = 0; i < 4; i++)
            o1[(bh * NN + n + i) * DD + d] = (short)f2bf(acc[rf][jf][i]);
        } else {
          U4 p;
#pragma unroll
          for (int i = 0; i < 4; i++) p.s[i] = f2bf(acc[rf][jf][i]);
          *(unsigned long long*)&o2[(bh * DD + d) * NN + n] = p.ll;
        }
      }
    }
  } else {
#pragma unroll
    for (int jf = 0; jf < 4; jf++) {
      const int c = n0 + wc + jf * 16 + lrow;
      const int h = c >> 6, d = c & 63;
      const float bi = bias[c];
#pragma unroll
      for (int rf = 0; rf < 4; rf++) {
        const int r = m0 + wr + rf * 16 + ((lane >> 4) << 2);
        const int b = r >> 12, n = r & 4095;
        const int bh = b * HH + h;
        U4 v;
        v.ll = *(const unsigned long long*)&o2[(bh * DD + d) * NN + n];
#pragma unroll
        for (int i = 0; i < 4; i++)
          fout[(r + i) * CC + c] = acc[rf][jf][i] + bi + bf2f(v.s[i]);
      }
    }
  }
}

// ---------- landmark means ----------
__global__ void landmarks(const short* __restrict__ Qb, const short* __restrict__ Kb,
                          short* __restrict__ Qlmb, short* __restrict__ Klmb,
                          float* __restrict__ QlmF, float* __restrict__ KlmF) {
  int bh = blockIdx.y, l = blockIdx.x, d = threadIdx.x;
  const short* qp = Qb + (bh * NN + l * 64) * DD + d;
  const short* kp = Kb + (bh * NN + l * 64) * DD + d;
  float sq = 0.f, sk = 0.f;
  for (int s = 0; s < 64; s++) {
    sq += bf2f((unsigned short)qp[s * DD]);
    sk += bf2f((unsigned short)kp[s * DD]);
  }
  sq *= (1.f / 64.f); sk *= (1.f / 64.f);
  int o = bh * (LL * DD) + l * DD + d;
  Qlmb[o] = (short)f2bf(sq); Klmb[o] = (short)f2bf(sk);
  QlmF[o] = sq; KlmF[o] = sk;
}

// ---------- kernel3 logits: S3^T = K @ Qlm^T, write exp() + per-col partial sums ----------
__global__ __launch_bounds__(256) void e1_logits(
    const short* __restrict__ Kb, const short* __restrict__ Qlmb,
    short* __restrict__ P3u, float* __restrict__ s3part) {
  int bh = blockIdx.y, n0 = blockIdx.x * 128;
  __shared__ short Qlm[64 * 72];
  int t = threadIdx.x;
  for (int r = 0; r < 2; r++) {
    int e = t + r * 256;
    *(bf16x8*)&Qlm[(e >> 3) * 72 + (e & 7) * 8] = *(const bf16x8*)&Qlmb[bh * 4096 + e * 8];
  }
  __syncthreads();
  int wave = t >> 6, lane = t & 63, lrow = lane & 15, lk = (lane >> 4) << 3;
  int nw = n0 + wave * 32;
  bf16x8 aK[2][2];
#pragma unroll
  for (int rf = 0; rf < 2; rf++)
#pragma unroll
    for (int ks = 0; ks < 2; ks++)
      aK[rf][ks] = *(const bf16x8*)&Kb[(bh * NN + nw + rf * 16 + lrow) * DD + ks * 32 + lk];
  f32x4 acc[2][4];
#pragma unroll
  for (int rf = 0; rf < 2; rf++)
#pragma unroll
    for (int lf = 0; lf < 4; lf++) acc[rf][lf] = fzero4();
#pragma unroll
  for (int ks = 0; ks < 2; ks++) {
    bf16x8 bq[4];
#pragma unroll
    for (int lf = 0; lf < 4; lf++)
      bq[lf] = *(const bf16x8*)&Qlm[(lf * 16 + lrow) * 72 + ks * 32 + lk];
#pragma unroll
    for (int rf = 0; rf < 2; rf++)
#pragma unroll
      for (int lf = 0; lf < 4; lf++)
        acc[rf][lf] = __builtin_amdgcn_mfma_f32_16x16x32_bf16(aK[rf][ks], bq[lf], acc[rf][lf], 0, 0, 0);
  }
#pragma unroll
  for (int lf = 0; lf < 4; lf++) {
    float cp = 0.f;
#pragma unroll
    for (int rf = 0; rf < 2; rf++) {
      U4 p;
#pragma unroll
      for (int i = 0; i < 4; i++) {
        float e = expf(acc[rf][lf][i]);   // logits tiny (sd~0.04): no max needed
        p.s[i] = f2bf(e); cp += e;
      }
      int l = lf * 16 + lrow;
      int n = nw + rf * 16 + ((lane >> 4) << 2);
      *(unsigned long long*)&P3u[(bh * LL + l) * NN + n] = p.ll;
    }
    cp += __shfl_xor(cp, 16);
    cp += __shfl_xor(cp, 32);
    if (lane < 16)
      s3part[((bh * 32 + blockIdx.x) * 4 + wave) * LL + lf * 16 + lane] = cp;
  }
}

// ---------- k3V^T[d][l] = (VT @ P3u^T) / colsum ----------
__global__ __launch_bounds__(256) void e2_pv(
    const short* __restrict__ VTb, const short* __restrict__ P3u,
    const float* __restrict__ s3part, float* __restrict__ k3VT) {
  int bh = blockIdx.x;
  int wave = threadIdx.x >> 6, lane = threadIdx.x & 63, lrow = lane & 15, lk = (lane >> 4) << 3;
  const short* ap = VTb + (bh * DD + wave * 16 + lrow) * NN + lk;
  const short* bp = P3u + (bh * LL + lrow) * NN + lk;
  f32x4 acc[4];
#pragma unroll
  for (int lf = 0; lf < 4; lf++) acc[lf] = fzero4();
  for (int nb = 0; nb < NN; nb += 32) {
    bf16x8 a = *(const bf16x8*)(ap + nb);
#pragma unroll
    for (int lf = 0; lf < 4; lf++) {
      bf16x8 b = *(const bf16x8*)(bp + lf * 16 * NN + nb);
      acc[lf] = __builtin_amdgcn_mfma_f32_16x16x32_bf16(a, b, acc[lf], 0, 0, 0);
    }
  }
#pragma unroll
  for (int lf = 0; lf < 4; lf++) {
    int l = lf * 16 + lrow;
    float s = 0.f;
    for (int i2 = 0; i2 < 128; i2++) s += s3part[(bh * 128 + i2) * LL + l];
    float rs = 1.f / s;
#pragma unroll
    for (int i = 0; i < 4; i++) {
      int dd = wave * 16 + ((lane >> 4) << 2) + i;
      k3VT[(bh * DD + dd) * LL + l] = acc[lf][i] * rs;
    }
  }
}

// ---------- per-(b,h): kernel2 softmax + Newton-Schulz inverse + M = inv @ k3V ----------
__device__ __forceinline__ void mm64(const float* X, const float* Y, int row, int c0, float o[8]) {
#pragma unroll
  for (int j = 0; j < 8; j++) o[j] = 0.f;
  for (int k = 0; k < 64; k++) {
    float x = X[row * 68 + k];
    const float4* yp = (const float4*)&Y[k * 68 + c0];
    float4 y0 = yp[0], y1 = yp[1];
    o[0] += x * y0.x; o[1] += x * y0.y; o[2] += x * y0.z; o[3] += x * y0.w;
    o[4] += x * y1.x; o[5] += x * y1.y; o[6] += x * y1.z; o[7] += x * y1.w;
  }
}

__global__ __launch_bounds__(512) void newton_inv(
    const float* __restrict__ QlmF, const float* __restrict__ KlmF,
    const float* __restrict__ k3VT, short* __restrict__ MTws) {
  __shared__ float A_[64 * 68], B_[64 * 68], C_[64 * 68], D_[64 * 68], E_[64 * 68];
  __shared__ float red[64];
  __shared__ float denom_s;
  int bh = blockIdx.x, t = threadIdx.x;
  int row = t >> 3, c0 = (t & 7) << 3;
#pragma unroll
  for (int i = 0; i < 8; i++) {
    int e = t * 8 + i;
    A_[(e >> 6) * 68 + (e & 63)] = QlmF[bh * 4096 + e];
    B_[(e >> 6) * 68 + (e & 63)] = KlmF[bh * 4096 + e];
  }
  __syncthreads();
  {  // S2 = Qlm @ Klm^T ; softmax rows -> C_
    float4 ar[16];
#pragma unroll
    for (int q = 0; q < 16; q++) ar[q] = *(const float4*)&A_[row * 68 + q * 4];
    float o[8];
#pragma unroll
    for (int mm = 0; mm < 8; mm++) {
      const float4* br = (const float4*)&B_[(c0 + mm) * 68];
      float s = 0.f;
      for (int q = 0; q < 16; q++) {
        float4 b4 = br[q];
        s += ar[q].x * b4.x + ar[q].y * b4.y + ar[q].z * b4.z + ar[q].w * b4.w;
      }
      o[mm] = s;
    }
    float mx = o[0];
#pragma unroll
    for (int mm = 1; mm < 8; mm++) mx = fmaxf(mx, o[mm]);
    mx = fmaxf(mx, __shfl_xor(mx, 1));
    mx = fmaxf(mx, __shfl_xor(mx, 2));
    mx = fmaxf(mx, __shfl_xor(mx, 4));
    float ss = 0.f;
#pragma unroll
    for (int mm = 0; mm < 8; mm++) { o[mm] = expf(o[mm] - mx); ss += o[mm]; }
    ss += __shfl_xor(ss, 1); ss += __shfl_xor(ss, 2); ss += __shfl_xor(ss, 4);
    float r = 1.f / ss;
#pragma unroll
    for (int mm = 0; mm < 8; mm++) C_[row * 68 + c0 + mm] = o[mm] * r;
  }
  __syncthreads();
  if (t < 64) {
    float s = 0.f;
    for (int l2 = 0; l2 < 64; l2++) s += C_[l2 * 68 + t];
    red[t] = s;
  }
  __syncthreads();
  if (t == 0) {
    float m = red[0];
    for (int i = 1; i < 64; i++) m = fmaxf(m, red[i]);
    denom_s = m;
  }
  __syncthreads();
  {
    float rdn = 1.f / denom_s;
#pragma unroll
    for (int i = 0; i < 8; i++) D_[row * 68 + c0 + i] = C_[(c0 + i) * 68 + row] * rdn;
  }
  __syncthreads();
  float* Vc = D_;
  float* t1 = A_;
  float* t2 = B_;
  float* t3 = E_;
  float o[8];
  for (int it = 0; it < 6; it++) {
    mm64(C_, Vc, row, c0, o);                       // KV
#pragma unroll
    for (int j = 0; j < 8; j++) t1[row * 68 + c0 + j] = o[j];
    __syncthreads();
    mm64(t1, t1, row, c0, o);                       // KV@KV
#pragma unroll
    for (int j = 0; j < 8; j++) t2[row * 68 + c0 + j] = 7.f * t1[row * 68 + c0 + j] - o[j];
    __syncthreads();
    mm64(t1, t2, row, c0, o);                       // KV@(7I-KV)
#pragma unroll
    for (int j = 0; j < 8; j++) t3[row * 68 + c0 + j] = 15.f * t1[row * 68 + c0 + j] - o[j];
    __syncthreads();
    mm64(Vc, t3, row, c0, o);                       // V@(13I - T3)
#pragma unroll
    for (int j = 0; j < 8; j++) t2[row * 68 + c0 + j] = 0.25f * (13.f * Vc[row * 68 + c0 + j] - o[j]);
    __syncthreads();
    float* tmp = Vc; Vc = t2; t2 = tmp;
  }
  // M^T[d][j] = sum_m inv[j][m] * k3V[m][d]  (k3VT[d][m] staged into t1)
#pragma unroll
  for (int i = 0; i < 8; i++) {
    int e = t * 8 + i;
    t1[(e >> 6) * 68 + (e & 63)] = k3VT[bh * 4096 + e];
  }
  __syncthreads();
  {
    float4 ar[16];
#pragma unroll
    for (int q = 0; q < 16; q++) ar[q] = *(const float4*)&t1[row * 68 + q * 4];
    for (int jj = 0; jj < 8; jj++) {
      const float4* dr = (const float4*)&Vc[(c0 + jj) * 68];
      float s = 0.f;
      for (int q = 0; q < 16; q++) {
        float4 d4 = dr[q];
        s += ar[q].x * d4.x + ar[q].y * d4.y + ar[q].z * d4.z + ar[q].w * d4.w;
      }
      MTws[bh * 4096 + row * 64 + c0 + jj] = (short)f2bf(s);
    }
  }
}

// ---------- kernel1 softmax + @M  -> SV (in [B,N,C] bf16) ----------
__global__ __launch_bounds__(256) void pass2(
    const short* __restrict__ Qb, const short* __restrict__ Klmb,
    const short* __restrict__ MTws, short* __restrict__ SVb) {
  int bh = blockIdx.y, n0 = blockIdx.x * 128;
  int bb = bh / HH, hh = bh % HH;
  __shared__ short Klm[64 * 72];
  __shared__ short Mt[64 * 72];
  __shared__ short Pl[128 * 72];
  int t = threadIdx.x;
  for (int r = 0; r < 2; r++) {
    int e = t + r * 256;
    *(bf16x8*)&Klm[(e >> 3) * 72 + (e & 7) * 8] = *(const bf16x8*)&Klmb[bh * 4096 + e * 8];
    *(bf16x8*)&Mt[(e >> 3) * 72 + (e & 7) * 8]  = *(const bf16x8*)&MTws[bh * 4096 + e * 8];
  }
  __syncthreads();
  int wave = t >> 6, lane = t & 63, lrow = lane & 15, lk = (lane >> 4) << 3;
  int nw = wave * 32;
  bf16x8 aQ[2][2];
#pragma unroll
  for (int rf = 0; rf < 2; rf++)
#pragma unroll
    for (int ks = 0; ks < 2; ks++)
      aQ[rf][ks] = *(const bf16x8*)&Qb[(bh * NN + n0 + nw + rf * 16 + lrow) * DD + ks * 32 + lk];
  f32x4 s[2][4];
#pragma unroll
  for (int rf = 0; rf < 2; rf++)
#pragma unroll
    for (int jf = 0; jf < 4; jf++) s[rf][jf] = fzero4();
#pragma unroll
  for (int ks = 0; ks < 2; ks++) {
    bf16x8 bk[4];
#pragma unroll
    for (int jf = 0; jf < 4; jf++)
      bk[jf] = *(const bf16x8*)&Klm[(jf * 16 + lrow) * 72 + ks * 32 + lk];
#pragma unroll
    for (int rf = 0; rf < 2; rf++)
#pragma unroll
      for (int jf = 0; jf < 4; jf++)
        s[rf][jf] = __builtin_amdgcn_mfma_f32_16x16x32_bf16(aQ[rf][ks], bk[jf], s[rf][jf], 0, 0, 0);
  }
#pragma unroll
  for (int rf = 0; rf < 2; rf++)
#pragma unroll
    for (int i = 0; i < 4; i++) {
      float v0 = s[rf][0][i], v1 = s[rf][1][i], v2 = s[rf][2][i], v3 = s[rf][3][i];
      float mx = fmaxf(fmaxf(v0, v1), fmaxf(v2, v3));
      mx = fmaxf(mx, __shfl_xor(mx, 1));
      mx = fmaxf(mx, __shfl_xor(mx, 2));
      mx = fmaxf(mx, __shfl_xor(mx, 4));
      mx = fmaxf(mx, __shfl_xor(mx, 8));
      v0 = expf(v0 - mx); v1 = expf(v1 - mx); v2 = expf(v2 - mx); v3 = expf(v3 - mx);
      float ss = v0 + v1 + v2 + v3;
      ss += __shfl_xor(ss, 1); ss += __shfl_xor(ss, 2);
      ss += __shfl_xor(ss, 4); ss += __shfl_xor(ss, 8);
      float rr = 1.f / ss;
      int n = nw + rf * 16 + ((lane >> 4) << 2) + i;
      Pl[n * 72 + 0  + lrow] = (short)f2bf(v0 * rr);
      Pl[n * 72 + 16 + lrow] = (short)f2bf(v1 * rr);
      Pl[n * 72 + 32 + lrow] = (short)f2bf(v2 * rr);
      Pl[n * 72 + 48 + lrow] = (short)f2bf(v3 * rr);
    }
  __syncthreads();
  f32x4 o[2][4];
#pragma unroll
  for (int rf = 0; rf < 2; rf++)
#pragma unroll
    for (int df = 0; df < 4; df++) o[rf][df] = fzero4();
#pragma unroll
  for (int ks = 0; ks < 2; ks++) {
    bf16x8 aP[2];
#pragma unroll
    for (int rf = 0; rf < 2; rf++)
      aP[rf] = *(const bf16x8*)&Pl[(nw + rf * 16 + lrow) * 72 + ks * 32 + lk];
    bf16x8 bm[4];
#pragma unroll
    for (int df = 0; df < 4; df++)
      bm[df] = *(const bf16x8*)&Mt[(df * 16 + lrow) * 72 + ks * 32 + lk];
#pragma unroll
    for (int rf = 0; rf < 2; rf++)
#pragma unroll
      for (int df = 0; df < 4; df++)
        o[rf][df] = __builtin_amdgcn_mfma_f32_16x16x32_bf16(aP[rf], bm[df], o[rf][df], 0, 0, 0);
  }
#pragma unroll
  for (int rf = 0; rf < 2; rf++)
#pragma unroll
    for (int df = 0; df < 4; df++)
#pragma unroll
      for (int i = 0; i < 4; i++) {
        int n = n0 + nw + rf * 16 + ((lane >> 4) << 2) + i;
        SVb[(bb * NN + n) * CC + hh * 64 + df * 16 + lrow] = (short)f2bf(o[rf][df][i]);
      }
}

extern "C" void kernel_launch(void* const* d_in, const int* in_sizes, int n_in,
                              void* d_out, int out_size, void* d_ws, size_t ws_size,
                              hipStream_t stream) {
  const float* x      = (const float*)d_in[0];
  const float* w_qkv  = (const float*)d_in[1];
  const float* w_proj = (const float*)d_in[2];
  const float* b_proj = (const float*)d_in[3];
  float* out = (float*)d_out;

  char* p = (char*)d_ws;
  auto alloc = [&](size_t bytes) -> char* {
    char* r = p; p += (bytes + 255) & ~(size_t)255; return r;
  };
  short* xb     = (short*)alloc((size_t)MM_ * KQKV * 2);
  short* wqkvT  = (short*)alloc((size_t)NQKV * KQKV * 2);
  short* wprojT = (short*)alloc((size_t)CC * CC * 2);
  short* Qb     = (short*)alloc((size_t)BH * NN * DD * 2);
  short* Kb     = (short*)alloc((size_t)BH * NN * DD * 2);
  short* VTb    = (short*)alloc((size_t)BH * DD * NN * 2);
  short* Qlmb   = (short*)alloc((size_t)BH * LL * DD * 2);
  short* Klmb   = (short*)alloc((size_t)BH * LL * DD * 2);
  float* QlmF   = (float*)alloc((size_t)BH * LL * DD * 4);
  float* KlmF   = (float*)alloc((size_t)BH * LL * DD * 4);
  float* s3part = (float*)alloc((size_t)BH * 128 * LL * 4);
  short* P3u    = (short*)alloc((size_t)BH * LL * NN * 2);
  float* k3VT   = (float*)alloc((size_t)BH * DD * LL * 4);
  short* MTws   = (short*)alloc((size_t)BH * DD * LL * 2);
  short* SVb    = (short*)alloc((size_t)MM_ * CC * 2);

  conv_bf16<<<(MM_ * KQKV / 4 + 255) / 256, 256, 0, stream>>>(x, xb, MM_ * KQKV / 4);
  transpose_bf16<<<dim3(NQKV / 32, KQKV / 32), 256, 0, stream>>>(w_qkv, wqkvT, KQKV, NQKV);
  transpose_bf16<<<dim3(CC / 32, CC / 32), 256, 0, stream>>>(w_proj, wprojT, CC, CC);
  gemm128<0><<<dim3(MM_ / 128, NQKV / 128), 256, 0, stream>>>(
      xb, wqkvT, Qb, Kb, VTb, nullptr, nullptr);
  landmarks<<<dim3(LL, BH), 64, 0, stream>>>(Qb, Kb, Qlmb, Klmb, QlmF, KlmF);
  e1_logits<<<dim3(NN / 128, BH), 256, 0, stream>>>(Kb, Qlmb, P3u, s3part);
  e2_pv<<<BH, 256, 0, stream>>>(VTb, P3u, s3part, k3VT);
  newton_inv<<<BH, 512, 0, stream>>>(QlmF, KlmF, k3VT, MTws);
  pass2<<<dim3(NN / 128, BH), 256, 0, stream>>>(Qb, Klmb, MTws, SVb);
  gemm128<1><<<dim3(MM_ / 128, CC / 128), 256, 0, stream>>>(
      SVb, wprojT, nullptr, nullptr, VTb, b_proj, out);
}

// Round 2
// 498.337 us; speedup vs baseline: 1.0768x; 1.0768x over previous
//
#include <hip/hip_runtime.h>
#include <math.h>

// ---------- problem constants ----------
#define BB   8
#define NN   4096
#define CC   768
#define HH   12
#define DD   64
#define LL   64
#define BH   96          // BB*HH
#define MM_  32768       // BB*NN
#define KQKV 768
#define NQKV 2304
#define NTILES 24        // K / 32

typedef short bf16x8 __attribute__((ext_vector_type(8)));
typedef float f32x4  __attribute__((ext_vector_type(4)));

union U4 { unsigned long long ll; unsigned short s[4]; };

__device__ __forceinline__ unsigned short f2bf(float f) {
  union { float f; unsigned u; } v; v.f = f;
  return (unsigned short)((v.u + 0x7FFFu + ((v.u >> 16) & 1u)) >> 16);
}
__device__ __forceinline__ float bf2f(unsigned short h) {
  union { unsigned u; float f; } v; v.u = ((unsigned)h) << 16;
  return v.f;
}
__device__ __forceinline__ f32x4 fzero4() {
  f32x4 z; z[0] = 0.f; z[1] = 0.f; z[2] = 0.f; z[3] = 0.f; return z;
}
__device__ __forceinline__ void gload_lds16(const void* g, void* l) {
  __builtin_amdgcn_global_load_lds(
      (const __attribute__((address_space(1))) void*)g,
      (__attribute__((address_space(3))) void*)l, 16, 0, 0);
}

// ---------- elementwise fp32 -> bf16 ----------
__global__ void conv_bf16(const float* __restrict__ in, short* __restrict__ out, int n4) {
  int i = blockIdx.x * 256 + threadIdx.x;
  if (i >= n4) return;
  float4 v = ((const float4*)in)[i];
  U4 p; p.s[0] = f2bf(v.x); p.s[1] = f2bf(v.y); p.s[2] = f2bf(v.z); p.s[3] = f2bf(v.w);
  ((unsigned long long*)out)[i] = p.ll;
}

// ---------- transpose fp32[R][C] -> bf16[C][R] ----------
__global__ __launch_bounds__(256) void transpose_bf16(
    const float* __restrict__ in, short* __restrict__ out, int R, int C) {
  __shared__ float tile[32][33];
  int c0 = blockIdx.x * 32, r0 = blockIdx.y * 32;
  int tx = threadIdx.x & 31, ty = threadIdx.x >> 5;
  for (int i = ty; i < 32; i += 8)
    tile[i][tx] = in[(r0 + i) * C + c0 + tx];
  __syncthreads();
  for (int i = ty; i < 32; i += 8)
    out[(c0 + i) * R + r0 + tx] = (short)f2bf(tile[tx][i]);
}

// ---------- 256x256 bf16 MFMA GEMM, phased schedule, counted vmcnt ----------
// 8 waves (2Mx4N), BK=32, 4 LDS buffers (128 KiB), prefetch 3 K-tiles ahead.
// LDS swizzle: within 64B rows, byte bits 4-5 ^= row bits 1-2 (involution);
// global source pre-swizzled so global_load_lds' linear write lands swizzled.
// EPI 0: qkv  (A=xb,  B=wqkvT)  -> Qb (scaled 1/8), Kb, VTb (transposed V)
// EPI 1: proj (A=SVb, B=wprojT) -> fout = acc + bias + V-residual (from VTb)
template <int EPI>
__global__ __launch_bounds__(512, 2) void gemm256(
    const short* __restrict__ A, const short* __restrict__ Bw,
    short* __restrict__ o0, short* __restrict__ o1, short* __restrict__ o2,
    const float* __restrict__ bias, float* __restrict__ fout) {
  __shared__ short L[65536];   // 128 KiB: buf b at b*32768 bytes (A 16KB | B 16KB)
  const int t = threadIdx.x;
  const int wave = t >> 6, lane = t & 63;
  const int wm = wave >> 2, wn = wave & 3;
  const int lrow = lane & 15, g = lane >> 4;

  // XCD-bijective block swizzle (gridDim.x % 8 == 0 for both uses)
  const int q8 = gridDim.x >> 3;
  const int wg = ((int)blockIdx.x & 7) * q8 + ((int)blockIdx.x >> 3);
  const int tm = wg & 127, tn = wg >> 7;
  const int m0 = tm << 8, n0 = tn << 8;

  // staging: thread stages 16B slots t*16 and t*16+8192 of each 16KB chunk.
  // slot s holds element (row = s>>6, colslot = ((s>>4)^(s>>7))&3)
  const int csl = (((t & 3) ^ ((t >> 3) & 3)) << 3);   // source col (elements)
  const short* pA0 = A  + (size_t)(m0 + (t >> 2)) * KQKV + csl;
  const short* pA1 = pA0 + 128 * KQKV;
  const short* pB0 = Bw + (size_t)(n0 + (t >> 2)) * KQKV + csl;
  const short* pB1 = pB0 + 128 * KQKV;
  char* ldsA = (char*)L + wave * 1024;      // + buf*32768 (+8192 for rows 128..255)
  char* ldsB = ldsA + 16384;

  // fragment read addressing (swizzled): byte = r*64 + ((g ^ ((lrow>>1)&3))<<4)
  const int swz16 = ((g ^ ((lrow >> 1) & 3)) << 4);
  const int aoff = (wm * 128 + lrow) * 64 + swz16;            // + mh*4096 + m*1024
  const int boff = 16384 + (wn * 64 + lrow) * 64 + swz16;     // + nf*1024

  f32x4 acc[8][4];
#pragma unroll
  for (int i = 0; i < 8; ++i)
#pragma unroll
    for (int j = 0; j < 4; ++j) acc[i][j] = fzero4();

  // ---- prologue: stage tiles 0..2 ----
#pragma unroll
  for (int T = 0; T < 3; ++T) {
    gload_lds16(pA0 + T * 32, ldsA + T * 32768);
    gload_lds16(pA1 + T * 32, ldsA + T * 32768 + 8192);
    gload_lds16(pB0 + T * 32, ldsB + T * 32768);
    gload_lds16(pB1 + T * 32, ldsB + T * 32768 + 8192);
  }
  asm volatile("s_waitcnt vmcnt(8)" ::: "memory");
  __builtin_amdgcn_s_barrier();

  for (int T = 0; T < NTILES; ++T) {
    const char* Lb = (const char*)L + (T & 3) * 32768;
    const int Ts = T + 3;
    const int sb = (Ts & 3) * 32768;
    bf16x8 a[4], b[4];
    // ================= phase 1: quadrant mh=0 =================
#pragma unroll
    for (int nf = 0; nf < 4; ++nf) b[nf] = *(const bf16x8*)(Lb + boff + nf * 1024);
#pragma unroll
    for (int m = 0; m < 4; ++m)  a[m] = *(const bf16x8*)(Lb + aoff + m * 1024);
    if (Ts < NTILES) {
      gload_lds16(pA0 + Ts * 32, ldsA + sb);
      gload_lds16(pA1 + Ts * 32, ldsA + sb + 8192);
    }
    __builtin_amdgcn_sched_barrier(0);
    __builtin_amdgcn_s_barrier();
    asm volatile("s_waitcnt lgkmcnt(0)" ::: "memory");
    __builtin_amdgcn_sched_barrier(0);
    __builtin_amdgcn_s_setprio(1);
#pragma unroll
    for (int m = 0; m < 4; ++m)
#pragma unroll
      for (int nf = 0; nf < 4; ++nf)
        acc[m][nf] = __builtin_amdgcn_mfma_f32_16x16x32_bf16(a[m], b[nf], acc[m][nf], 0, 0, 0);
    __builtin_amdgcn_s_setprio(0);
    __builtin_amdgcn_sched_barrier(0);
    __builtin_amdgcn_s_barrier();
    // ================= phase 2: quadrant mh=1 =================
#pragma unroll
    for (int m = 0; m < 4; ++m)  a[m] = *(const bf16x8*)(Lb + aoff + 4096 + m * 1024);
    if (Ts < NTILES) {
      gload_lds16(pB0 + Ts * 32, ldsB + sb);
      gload_lds16(pB1 + Ts * 32, ldsB + sb + 8192);
    }
    __builtin_amdgcn_sched_barrier(0);
    __builtin_amdgcn_s_barrier();
    asm volatile("s_waitcnt lgkmcnt(0)" ::: "memory");
    __builtin_amdgcn_sched_barrier(0);
    __builtin_amdgcn_s_setprio(1);
#pragma unroll
    for (int m = 0; m < 4; ++m)
#pragma unroll
      for (int nf = 0; nf < 4; ++nf)
        acc[4 + m][nf] = __builtin_amdgcn_mfma_f32_16x16x32_bf16(a[m], b[nf], acc[4 + m][nf], 0, 0, 0);
    __builtin_amdgcn_s_setprio(0);
    __builtin_amdgcn_sched_barrier(0);
    // tile-end counted vmcnt: tiles T+2,T+3 may stay in flight; T+1 must land
    if (T < NTILES - 3)       { asm volatile("s_waitcnt vmcnt(8)" ::: "memory"); }
    else if (T == NTILES - 3) { asm volatile("s_waitcnt vmcnt(4)" ::: "memory"); }
    else if (T == NTILES - 2) { asm volatile("s_waitcnt vmcnt(0)" ::: "memory"); }
    __builtin_amdgcn_s_barrier();
  }

  // ================= epilogue =================
  if constexpr (EPI == 0) {
    const int three = tn / 3;
    const int ccb = (tn % 3) * 256;
#pragma unroll
    for (int nf = 0; nf < 4; ++nf) {
      const int cc = ccb + wn * 64 + nf * 16 + lrow;
      const int h = cc >> 6, d = cc & 63;
#pragma unroll
      for (int mf = 0; mf < 8; ++mf) {
        const int r = m0 + wm * 128 + mf * 16 + g * 4;
        const int bb = r >> 12, n = r & 4095;
        const size_t bh = (size_t)(bb * HH + h);
        if (three == 0) {
#pragma unroll
          for (int i = 0; i < 4; ++i)
            o0[(bh * NN + n + i) * DD + d] = (short)f2bf(acc[mf][nf][i] * 0.125f);
        } else if (three == 1) {
#pragma unroll
          for (int i = 0; i < 4; ++i)
            o1[(bh * NN + n + i) * DD + d] = (short)f2bf(acc[mf][nf][i]);
        } else {
          U4 p;
#pragma unroll
          for (int i = 0; i < 4; ++i) p.s[i] = f2bf(acc[mf][nf][i]);
          *(unsigned long long*)&o2[(bh * DD + d) * NN + n] = p.ll;
        }
      }
    }
  } else {
#pragma unroll
    for (int nf = 0; nf < 4; ++nf) {
      const int c = n0 + wn * 64 + nf * 16 + lrow;
      const int h = c >> 6, d = c & 63;
      const float bi = bias[c];
#pragma unroll
      for (int mf = 0; mf < 8; ++mf) {
        const int r = m0 + wm * 128 + mf * 16 + g * 4;
        const int bb = r >> 12, n = r & 4095;
        U4 v;
        v.ll = *(const unsigned long long*)&o2[((size_t)(bb * HH + h) * DD + d) * NN + n];
#pragma unroll
        for (int i = 0; i < 4; ++i)
          fout[(size_t)(r + i) * CC + c] = acc[mf][nf][i] + bi + bf2f(v.s[i]);
      }
    }
  }
}

// ---------- landmark means (coalesced bf16x8 + shfl reduce) ----------
__global__ __launch_bounds__(64) void landmarks(
    const short* __restrict__ Qb, const short* __restrict__ Kb,
    short* __restrict__ Qlmb, short* __restrict__ Klmb,
    float* __restrict__ QlmF, float* __restrict__ KlmF) {
  int bh = blockIdx.y, l = blockIdx.x, t = threadIdx.x;
  int rg = t >> 3, dg = t & 7;
  const short* qp = Qb + ((size_t)bh * NN + l * 64 + rg) * DD + dg * 8;
  const short* kp = Kb + ((size_t)bh * NN + l * 64 + rg) * DD + dg * 8;
  float sq[8], sk[8];
#pragma unroll
  for (int j = 0; j < 8; ++j) { sq[j] = 0.f; sk[j] = 0.f; }
  for (int s = 0; s < 8; ++s) {
    bf16x8 qv = *(const bf16x8*)(qp + (size_t)s * 8 * DD);
    bf16x8 kv = *(const bf16x8*)(kp + (size_t)s * 8 * DD);
#pragma unroll
    for (int j = 0; j < 8; ++j) {
      sq[j] += bf2f((unsigned short)qv[j]);
      sk[j] += bf2f((unsigned short)kv[j]);
    }
  }
#pragma unroll
  for (int j = 0; j < 8; ++j) {
    sq[j] += __shfl_xor(sq[j], 8); sq[j] += __shfl_xor(sq[j], 16); sq[j] += __shfl_xor(sq[j], 32);
    sk[j] += __shfl_xor(sk[j], 8); sk[j] += __shfl_xor(sk[j], 16); sk[j] += __shfl_xor(sk[j], 32);
  }
  if (t < 8) {
    int o = bh * 4096 + l * 64 + dg * 8;
#pragma unroll
    for (int j = 0; j < 8; ++j) {
      float q = sq[j] * (1.f / 64.f), k = sk[j] * (1.f / 64.f);
      Qlmb[o + j] = (short)f2bf(q); Klmb[o + j] = (short)f2bf(k);
      QlmF[o + j] = q; KlmF[o + j] = k;
    }
  }
}

// ---------- kernel3 logits: S3^T = K @ Qlm^T, write exp() + per-col partial sums ----------
__global__ __launch_bounds__(256) void e1_logits(
    const short* __restrict__ Kb, const short* __restrict__ Qlmb,
    short* __restrict__ P3u, float* __restrict__ s3part) {
  int bh = blockIdx.y, n0 = blockIdx.x * 128;
  __shared__ short Qlm[64 * 72];
  int t = threadIdx.x;
  for (int r = 0; r < 2; r++) {
    int e = t + r * 256;
    *(bf16x8*)&Qlm[(e >> 3) * 72 + (e & 7) * 8] = *(const bf16x8*)&Qlmb[bh * 4096 + e * 8];
  }
  __syncthreads();
  int wave = t >> 6, lane = t & 63, lrow = lane & 15, lk = (lane >> 4) << 3;
  int nw = n0 + wave * 32;
  bf16x8 aK[2][2];
#pragma unroll
  for (int rf = 0; rf < 2; rf++)
#pragma unroll
    for (int ks = 0; ks < 2; ks++)
      aK[rf][ks] = *(const bf16x8*)&Kb[((size_t)bh * NN + nw + rf * 16 + lrow) * DD + ks * 32 + lk];
  f32x4 acc[2][4];
#pragma unroll
  for (int rf = 0; rf < 2; rf++)
#pragma unroll
    for (int lf = 0; lf < 4; lf++) acc[rf][lf] = fzero4();
#pragma unroll
  for (int ks = 0; ks < 2; ks++) {
    bf16x8 bq[4];
#pragma unroll
    for (int lf = 0; lf < 4; lf++)
      bq[lf] = *(const bf16x8*)&Qlm[(lf * 16 + lrow) * 72 + ks * 32 + lk];
#pragma unroll
    for (int rf = 0; rf < 2; rf++)
#pragma unroll
      for (int lf = 0; lf < 4; lf++)
        acc[rf][lf] = __builtin_amdgcn_mfma_f32_16x16x32_bf16(aK[rf][ks], bq[lf], acc[rf][lf], 0, 0, 0);
  }
#pragma unroll
  for (int lf = 0; lf < 4; lf++) {
    float cp = 0.f;
#pragma unroll
    for (int rf = 0; rf < 2; rf++) {
      U4 p;
#pragma unroll
      for (int i = 0; i < 4; i++) {
        float e = expf(acc[rf][lf][i]);   // logits tiny (sd~0.04): no max needed
        p.s[i] = f2bf(e); cp += e;
      }
      int l = lf * 16 + lrow;
      int n = nw + rf * 16 + ((lane >> 4) << 2);
      *(unsigned long long*)&P3u[((size_t)bh * LL + l) * NN + n] = p.ll;
    }
    cp += __shfl_xor(cp, 16);
    cp += __shfl_xor(cp, 32);
    if (lane < 16)
      s3part[((bh * 32 + blockIdx.x) * 4 + wave) * LL + lf * 16 + lane] = cp;
  }
}

// ---------- k3V^T partials: k3VTp[ch][d][l] = VT[:, ch-chunk] @ P3u[:, ch-chunk]^T ----------
__global__ __launch_bounds__(256) void e2_pv(
    const short* __restrict__ VTb, const short* __restrict__ P3u,
    float* __restrict__ k3VTp) {
  int bh = blockIdx.x, ch = blockIdx.y;
  int wave = threadIdx.x >> 6, lane = threadIdx.x & 63, lrow = lane & 15, lk = (lane >> 4) << 3;
  const short* ap = VTb + ((size_t)bh * DD + wave * 16 + lrow) * NN + ch * 512 + lk;
  const short* bp = P3u + ((size_t)bh * LL + lrow) * NN + ch * 512 + lk;
  f32x4 acc[4];
#pragma unroll
  for (int lf = 0; lf < 4; lf++) acc[lf] = fzero4();
  for (int nb = 0; nb < 512; nb += 32) {
    bf16x8 a = *(const bf16x8*)(ap + nb);
#pragma unroll
    for (int lf = 0; lf < 4; lf++) {
      bf16x8 b = *(const bf16x8*)(bp + (size_t)lf * 16 * NN + nb);
      acc[lf] = __builtin_amdgcn_mfma_f32_16x16x32_bf16(a, b, acc[lf], 0, 0, 0);
    }
  }
#pragma unroll
  for (int lf = 0; lf < 4; lf++) {
    int l = lf * 16 + lrow;
#pragma unroll
    for (int i = 0; i < 4; i++) {
      int dd = wave * 16 + ((lane >> 4) << 2) + i;
      k3VTp[((size_t)ch * BH + bh) * 4096 + dd * 64 + l] = acc[lf][i];
    }
  }
}

// ---------- per-(b,h): kernel2 softmax + Newton-Schulz inverse + M = inv @ k3V ----------
__device__ __forceinline__ void mm64(const float* X, const float* Y, int row, int c0, float o[8]) {
#pragma unroll
  for (int j = 0; j < 8; j++) o[j] = 0.f;
  for (int k = 0; k < 64; k++) {
    float x = X[row * 68 + k];
    const float4* yp = (const float4*)&Y[k * 68 + c0];
    float4 y0 = yp[0], y1 = yp[1];
    o[0] += x * y0.x; o[1] += x * y0.y; o[2] += x * y0.z; o[3] += x * y0.w;
    o[4] += x * y1.x; o[5] += x * y1.y; o[6] += x * y1.z; o[7] += x * y1.w;
  }
}

__global__ __launch_bounds__(512) void newton_inv(
    const float* __restrict__ QlmF, const float* __restrict__ KlmF,
    const float* __restrict__ k3VTp, const float* __restrict__ s3part,
    short* __restrict__ MTws) {
  __shared__ float A_[64 * 68], B_[64 * 68], C_[64 * 68], D_[64 * 68], E_[64 * 68];
  __shared__ float red[64];
  __shared__ float denom_s;
  int bh = blockIdx.x, t = threadIdx.x;
  int row = t >> 3, c0 = (t & 7) << 3;
#pragma unroll
  for (int i = 0; i < 8; i++) {
    int e = t * 8 + i;
    A_[(e >> 6) * 68 + (e & 63)] = QlmF[bh * 4096 + e];
    B_[(e >> 6) * 68 + (e & 63)] = KlmF[bh * 4096 + e];
  }
  __syncthreads();
  {  // S2 = Qlm @ Klm^T ; softmax rows -> C_
    float4 ar[16];
#pragma unroll
    for (int q = 0; q < 16; q++) ar[q] = *(const float4*)&A_[row * 68 + q * 4];
    float o[8];
#pragma unroll
    for (int mm = 0; mm < 8; mm++) {
      const float4* br = (const float4*)&B_[(c0 + mm) * 68];
      float s = 0.f;
      for (int q = 0; q < 16; q++) {
        float4 b4 = br[q];
        s += ar[q].x * b4.x + ar[q].y * b4.y + ar[q].z * b4.z + ar[q].w * b4.w;
      }
      o[mm] = s;
    }
    float mx = o[0];
#pragma unroll
    for (int mm = 1; mm < 8; mm++) mx = fmaxf(mx, o[mm]);
    mx = fmaxf(mx, __shfl_xor(mx, 1));
    mx = fmaxf(mx, __shfl_xor(mx, 2));
    mx = fmaxf(mx, __shfl_xor(mx, 4));
    float ss = 0.f;
#pragma unroll
    for (int mm = 0; mm < 8; mm++) { o[mm] = expf(o[mm] - mx); ss += o[mm]; }
    ss += __shfl_xor(ss, 1); ss += __shfl_xor(ss, 2); ss += __shfl_xor(ss, 4);
    float r = 1.f / ss;
#pragma unroll
    for (int mm = 0; mm < 8; mm++) C_[row * 68 + c0 + mm] = o[mm] * r;
  }
  __syncthreads();
  if (t < 64) {
    float s = 0.f;
    for (int l2 = 0; l2 < 64; l2++) s += C_[l2 * 68 + t];
    red[t] = s;
  }
  __syncthreads();
  if (t == 0) {
    float m = red[0];
    for (int i = 1; i < 64; i++) m = fmaxf(m, red[i]);
    denom_s = m;
  }
  __syncthreads();
  {
    float rdn = 1.f / denom_s;
#pragma unroll
    for (int i = 0; i < 8; i++) D_[row * 68 + c0 + i] = C_[(c0 + i) * 68 + row] * rdn;
  }
  __syncthreads();
  float* Vc = D_;
  float* t1 = A_;
  float* t2 = B_;
  float* t3 = E_;
  float o[8];
  for (int it = 0; it < 6; it++) {
    mm64(C_, Vc, row, c0, o);                       // KV
#pragma unroll
    for (int j = 0; j < 8; j++) t1[row * 68 + c0 + j] = o[j];
    __syncthreads();
    mm64(t1, t1, row, c0, o);                       // KV@KV
#pragma unroll
    for (int j = 0; j < 8; j++) t2[row * 68 + c0 + j] = 7.f * t1[row * 68 + c0 + j] - o[j];
    __syncthreads();
    mm64(t1, t2, row, c0, o);                       // KV@(7I-KV)
#pragma unroll
    for (int j = 0; j < 8; j++) t3[row * 68 + c0 + j] = 15.f * t1[row * 68 + c0 + j] - o[j];
    __syncthreads();
    mm64(Vc, t3, row, c0, o);                       // V@(13I - T3)
#pragma unroll
    for (int j = 0; j < 8; j++) t2[row * 68 + c0 + j] = 0.25f * (13.f * Vc[row * 68 + c0 + j] - o[j]);
    __syncthreads();
    float* tmp = Vc; Vc = t2; t2 = tmp;
  }
  // reciprocal column sums of kernel3 (per landmark m)
  if (t < 64) {
    float s = 0.f;
    for (int i2 = 0; i2 < 128; i2++) s += s3part[(bh * 128 + i2) * LL + t];
    red[t] = 1.f / s;
  }
  __syncthreads();
  // stage t1[d][m] = (sum_chunks k3VTp) * (1/s_m)
#pragma unroll
  for (int i = 0; i < 8; i++) {
    int e = t * 8 + i;
    float s = 0.f;
#pragma unroll
    for (int c = 0; c < 8; c++) s += k3VTp[((size_t)c * BH + bh) * 4096 + e];
    t1[(e >> 6) * 68 + (e & 63)] = s * red[e & 63];
  }
  __syncthreads();
  {
    float4 ar[16];
#pragma unroll
    for (int q = 0; q < 16; q++) ar[q] = *(const float4*)&t1[row * 68 + q * 4];
    for (int jj = 0; jj < 8; jj++) {
      const float4* dr = (const float4*)&Vc[(c0 + jj) * 68];
      float s = 0.f;
      for (int q = 0; q < 16; q++) {
        float4 d4 = dr[q];
        s += ar[q].x * d4.x + ar[q].y * d4.y + ar[q].z * d4.z + ar[q].w * d4.w;
      }
      MTws[bh * 4096 + row * 64 + c0 + jj] = (short)f2bf(s);
    }
  }
}

// ---------- kernel1 softmax + @M  -> SV (in [B,N,C] bf16) ----------
__global__ __launch_bounds__(256) void pass2(
    const short* __restrict__ Qb, const short* __restrict__ Klmb,
    const short* __restrict__ MTws, short* __restrict__ SVb) {
  int bh = blockIdx.y, n0 = blockIdx.x * 128;
  int bb = bh / HH, hh = bh % HH;
  __shared__ short Klm[64 * 72];
  __shared__ short Mt[64 * 72];
  __shared__ short Pl[128 * 72];
  int t = threadIdx.x;
  for (int r = 0; r < 2; r++) {
    int e = t + r * 256;
    *(bf16x8*)&Klm[(e >> 3) * 72 + (e & 7) * 8] = *(const bf16x8*)&Klmb[bh * 4096 + e * 8];
    *(bf16x8*)&Mt[(e >> 3) * 72 + (e & 7) * 8]  = *(const bf16x8*)&MTws[bh * 4096 + e * 8];
  }
  __syncthreads();
  int wave = t >> 6, lane = t & 63, lrow = lane & 15, lk = (lane >> 4) << 3;
  int nw = wave * 32;
  bf16x8 aQ[2][2];
#pragma unroll
  for (int rf = 0; rf < 2; rf++)
#pragma unroll
    for (int ks = 0; ks < 2; ks++)
      aQ[rf][ks] = *(const bf16x8*)&Qb[((size_t)bh * NN + n0 + nw + rf * 16 + lrow) * DD + ks * 32 + lk];
  f32x4 s[2][4];
#pragma unroll
  for (int rf = 0; rf < 2; rf++)
#pragma unroll
    for (int jf = 0; jf < 4; jf++) s[rf][jf] = fzero4();
#pragma unroll
  for (int ks = 0; ks < 2; ks++) {
    bf16x8 bk[4];
#pragma unroll
    for (int jf = 0; jf < 4; jf++)
      bk[jf] = *(const bf16x8*)&Klm[(jf * 16 + lrow) * 72 + ks * 32 + lk];
#pragma unroll
    for (int rf = 0; rf < 2; rf++)
#pragma unroll
      for (int jf = 0; jf < 4; jf++)
        s[rf][jf] = __builtin_amdgcn_mfma_f32_16x16x32_bf16(aQ[rf][ks], bk[jf], s[rf][jf], 0, 0, 0);
  }
#pragma unroll
  for (int rf = 0; rf < 2; rf++)
#pragma unroll
    for (int i = 0; i < 4; i++) {
      float v0 = s[rf][0][i], v1 = s[rf][1][i], v2 = s[rf][2][i], v3 = s[rf][3][i];
      float mx = fmaxf(fmaxf(v0, v1), fmaxf(v2, v3));
      mx = fmaxf(mx, __shfl_xor(mx, 1));
      mx = fmaxf(mx, __shfl_xor(mx, 2));
      mx = fmaxf(mx, __shfl_xor(mx, 4));
      mx = fmaxf(mx, __shfl_xor(mx, 8));
      v0 = expf(v0 - mx); v1 = expf(v1 - mx); v2 = expf(v2 - mx); v3 = expf(v3 - mx);
      float ss = v0 + v1 + v2 + v3;
      ss += __shfl_xor(ss, 1); ss += __shfl_xor(ss, 2);
      ss += __shfl_xor(ss, 4); ss += __shfl_xor(ss, 8);
      float rr = 1.f / ss;
      int n = nw + rf * 16 + ((lane >> 4) << 2) + i;
      Pl[n * 72 + 0  + lrow] = (short)f2bf(v0 * rr);
      Pl[n * 72 + 16 + lrow] = (short)f2bf(v1 * rr);
      Pl[n * 72 + 32 + lrow] = (short)f2bf(v2 * rr);
      Pl[n * 72 + 48 + lrow] = (short)f2bf(v3 * rr);
    }
  __syncthreads();
  f32x4 o[2][4];
#pragma unroll
  for (int rf = 0; rf < 2; rf++)
#pragma unroll
    for (int df = 0; df < 4; df++) o[rf][df] = fzero4();
#pragma unroll
  for (int ks = 0; ks < 2; ks++) {
    bf16x8 aP[2];
#pragma unroll
    for (int rf = 0; rf < 2; rf++)
      aP[rf] = *(const bf16x8*)&Pl[(nw + rf * 16 + lrow) * 72 + ks * 32 + lk];
    bf16x8 bm[4];
#pragma unroll
    for (int df = 0; df < 4; df++)
      bm[df] = *(const bf16x8*)&Mt[(df * 16 + lrow) * 72 + ks * 32 + lk];
#pragma unroll
    for (int rf = 0; rf < 2; rf++)
#pragma unroll
      for (int df = 0; df < 4; df++)
        o[rf][df] = __builtin_amdgcn_mfma_f32_16x16x32_bf16(aP[rf], bm[df], o[rf][df], 0, 0, 0);
  }
#pragma unroll
  for (int rf = 0; rf < 2; rf++)
#pragma unroll
    for (int df = 0; df < 4; df++)
#pragma unroll
      for (int i = 0; i < 4; i++) {
        int n = n0 + nw + rf * 16 + ((lane >> 4) << 2) + i;
        SVb[((size_t)bb * NN + n) * CC + hh * 64 + df * 16 + lrow] = (short)f2bf(o[rf][df][i]);
      }
}

extern "C" void kernel_launch(void* const* d_in, const int* in_sizes, int n_in,
                              void* d_out, int out_size, void* d_ws, size_t ws_size,
                              hipStream_t stream) {
  const float* x      = (const float*)d_in[0];
  const float* w_qkv  = (const float*)d_in[1];
  const float* w_proj = (const float*)d_in[2];
  const float* b_proj = (const float*)d_in[3];
  float* out = (float*)d_out;

  char* p = (char*)d_ws;
  auto alloc = [&](size_t bytes) -> char* {
    char* r = p; p += (bytes + 255) & ~(size_t)255; return r;
  };
  short* xb     = (short*)alloc((size_t)MM_ * KQKV * 2);
  short* wqkvT  = (short*)alloc((size_t)NQKV * KQKV * 2);
  short* wprojT = (short*)alloc((size_t)CC * CC * 2);
  short* Qb     = (short*)alloc((size_t)BH * NN * DD * 2);
  short* Kb     = (short*)alloc((size_t)BH * NN * DD * 2);
  short* VTb    = (short*)alloc((size_t)BH * DD * NN * 2);
  short* Qlmb   = (short*)alloc((size_t)BH * LL * DD * 2);
  short* Klmb   = (short*)alloc((size_t)BH * LL * DD * 2);
  float* QlmF   = (float*)alloc((size_t)BH * LL * DD * 4);
  float* KlmF   = (float*)alloc((size_t)BH * LL * DD * 4);
  float* s3part = (float*)alloc((size_t)BH * 128 * LL * 4);
  short* P3u    = (short*)alloc((size_t)BH * LL * NN * 2);
  float* k3VTp  = (float*)alloc((size_t)8 * BH * DD * LL * 4);
  short* MTws   = (short*)alloc((size_t)BH * DD * LL * 2);
  short* SVb    = (short*)alloc((size_t)MM_ * CC * 2);

  conv_bf16<<<(MM_ * KQKV / 4 + 255) / 256, 256, 0, stream>>>(x, xb, MM_ * KQKV / 4);
  transpose_bf16<<<dim3(NQKV / 32, KQKV / 32), 256, 0, stream>>>(w_qkv, wqkvT, KQKV, NQKV);
  transpose_bf16<<<dim3(CC / 32, CC / 32), 256, 0, stream>>>(w_proj, wprojT, CC, CC);
  gemm256<0><<<dim3((MM_ / 256) * (NQKV / 256)), 512, 0, stream>>>(
      xb, wqkvT, Qb, Kb, VTb, nullptr, nullptr);
  landmarks<<<dim3(LL, BH), 64, 0, stream>>>(Qb, Kb, Qlmb, Klmb, QlmF, KlmF);
  e1_logits<<<dim3(NN / 128, BH), 256, 0, stream>>>(Kb, Qlmb, P3u, s3part);
  e2_pv<<<dim3(BH, 8), 256, 0, stream>>>(VTb, P3u, k3VTp);
  newton_inv<<<BH, 512, 0, stream>>>(QlmF, KlmF, k3VTp, s3part, MTws);
  pass2<<<dim3(NN / 128, BH), 256, 0, stream>>>(Qb, Klmb, MTws, SVb);
  gemm256<1><<<dim3((MM_ / 256) * (CC / 256)), 512, 0, stream>>>(
      SVb, wprojT, nullptr, nullptr, VTb, b_proj, out);
}

// Round 3
// 490.792 us; speedup vs baseline: 1.0933x; 1.0154x over previous
//
#include <hip/hip_runtime.h>
#include <math.h>

// ---------- problem constants ----------
#define BB   8
#define NN   4096
#define CC   768
#define HH   12
#define DD   64
#define LL   64
#define BH   96          // BB*HH
#define MM_  32768       // BB*NN
#define KQKV 768
#define NQKV 2304
#define NTILES 24        // K / 32

typedef short bf16x8 __attribute__((ext_vector_type(8)));
typedef float f32x4  __attribute__((ext_vector_type(4)));

union U4 { unsigned long long ll; unsigned short s[4]; };

__device__ __forceinline__ unsigned short f2bf(float f) {
  union { float f; unsigned u; } v; v.f = f;
  return (unsigned short)((v.u + 0x7FFFu + ((v.u >> 16) & 1u)) >> 16);
}
__device__ __forceinline__ float bf2f(unsigned short h) {
  union { unsigned u; float f; } v; v.u = ((unsigned)h) << 16;
  return v.f;
}
__device__ __forceinline__ f32x4 fzero4() {
  f32x4 z; z[0] = 0.f; z[1] = 0.f; z[2] = 0.f; z[3] = 0.f; return z;
}
__device__ __forceinline__ void gload_lds16(const void* g, void* l) {
  __builtin_amdgcn_global_load_lds(
      (const __attribute__((address_space(1))) void*)g,
      (__attribute__((address_space(3))) void*)l, 16, 0, 0);
}

// ---------- elementwise fp32 -> bf16 ----------
__global__ void conv_bf16(const float* __restrict__ in, short* __restrict__ out, int n4) {
  int i = blockIdx.x * 256 + threadIdx.x;
  if (i >= n4) return;
  float4 v = ((const float4*)in)[i];
  U4 p; p.s[0] = f2bf(v.x); p.s[1] = f2bf(v.y); p.s[2] = f2bf(v.z); p.s[3] = f2bf(v.w);
  ((unsigned long long*)out)[i] = p.ll;
}

// ---------- transpose fp32[R][C] -> bf16[C][R] ----------
__global__ __launch_bounds__(256) void transpose_bf16(
    const float* __restrict__ in, short* __restrict__ out, int R, int C) {
  __shared__ float tile[32][33];
  int c0 = blockIdx.x * 32, r0 = blockIdx.y * 32;
  int tx = threadIdx.x & 31, ty = threadIdx.x >> 5;
  for (int i = ty; i < 32; i += 8)
    tile[i][tx] = in[(r0 + i) * C + c0 + tx];
  __syncthreads();
  for (int i = ty; i < 32; i += 8)
    out[(c0 + i) * R + r0 + tx] = (short)f2bf(tile[tx][i]);
}

// ---------- 256x256 bf16 MFMA GEMM, phased schedule, counted vmcnt ----------
// EPI 0: qkv  (A=xb,  B=wqkvT)  -> Qb (scaled 1/8), Kb, Vb   (all [bh][n][d])
// EPI 1: proj (A=SVb, B=wprojT) -> fout = acc + bias + V-residual (Vb), via
//        LDS-bounce epilogue for fully-coalesced float4 stores.
template <int EPI>
__global__ __launch_bounds__(512, 2) void gemm256(
    const short* __restrict__ A, const short* __restrict__ Bw,
    short* __restrict__ o0, short* __restrict__ o1, short* __restrict__ o2,
    const float* __restrict__ bias, float* __restrict__ fout) {
  __shared__ short L[65536];   // 128 KiB: buf b at b*32768 bytes (A 16KB | B 16KB)
  const int t = threadIdx.x;
  const int wave = t >> 6, lane = t & 63;
  const int wm = wave >> 2, wn = wave & 3;
  const int lrow = lane & 15, g = lane >> 4;

  // XCD-bijective block swizzle (gridDim.x % 8 == 0 for both uses)
  const int q8 = gridDim.x >> 3;
  const int wg = ((int)blockIdx.x & 7) * q8 + ((int)blockIdx.x >> 3);
  const int tm = wg & 127, tn = wg >> 7;
  const int m0 = tm << 8, n0 = tn << 8;

  // staging: thread stages 16B slots t*16 and t*16+8192 of each 16KB chunk.
  const int csl = (((t & 3) ^ ((t >> 3) & 3)) << 3);   // source col (elements)
  const short* pA0 = A  + (size_t)(m0 + (t >> 2)) * KQKV + csl;
  const short* pA1 = pA0 + 128 * KQKV;
  const short* pB0 = Bw + (size_t)(n0 + (t >> 2)) * KQKV + csl;
  const short* pB1 = pB0 + 128 * KQKV;
  char* ldsA = (char*)L + wave * 1024;      // + buf*32768 (+8192 for rows 128..255)
  char* ldsB = ldsA + 16384;

  // fragment read addressing (swizzled): byte = r*64 + ((g ^ ((lrow>>1)&3))<<4)
  const int swz16 = ((g ^ ((lrow >> 1) & 3)) << 4);
  const int aoff = (wm * 128 + lrow) * 64 + swz16;            // + mh*4096 + m*1024
  const int boff = 16384 + (wn * 64 + lrow) * 64 + swz16;     // + nf*1024

  f32x4 acc[8][4];
#pragma unroll
  for (int i = 0; i < 8; ++i)
#pragma unroll
    for (int j = 0; j < 4; ++j) acc[i][j] = fzero4();

  // ---- prologue: stage tiles 0..2 ----
#pragma unroll
  for (int T = 0; T < 3; ++T) {
    gload_lds16(pA0 + T * 32, ldsA + T * 32768);
    gload_lds16(pA1 + T * 32, ldsA + T * 32768 + 8192);
    gload_lds16(pB0 + T * 32, ldsB + T * 32768);
    gload_lds16(pB1 + T * 32, ldsB + T * 32768 + 8192);
  }
  asm volatile("s_waitcnt vmcnt(8)" ::: "memory");
  __builtin_amdgcn_s_barrier();

  for (int T = 0; T < NTILES; ++T) {
    const char* Lb = (const char*)L + (T & 3) * 32768;
    const int Ts = T + 3;
    const int sb = (Ts & 3) * 32768;
    bf16x8 a[4], b[4];
    // ================= phase 1: quadrant mh=0 =================
#pragma unroll
    for (int nf = 0; nf < 4; ++nf) b[nf] = *(const bf16x8*)(Lb + boff + nf * 1024);
#pragma unroll
    for (int m = 0; m < 4; ++m)  a[m] = *(const bf16x8*)(Lb + aoff + m * 1024);
    if (Ts < NTILES) {
      gload_lds16(pA0 + Ts * 32, ldsA + sb);
      gload_lds16(pA1 + Ts * 32, ldsA + sb + 8192);
    }
    __builtin_amdgcn_sched_barrier(0);
    __builtin_amdgcn_s_barrier();
    asm volatile("s_waitcnt lgkmcnt(0)" ::: "memory");
    __builtin_amdgcn_sched_barrier(0);
    __builtin_amdgcn_s_setprio(1);
#pragma unroll
    for (int m = 0; m < 4; ++m)
#pragma unroll
      for (int nf = 0; nf < 4; ++nf)
        acc[m][nf] = __builtin_amdgcn_mfma_f32_16x16x32_bf16(a[m], b[nf], acc[m][nf], 0, 0, 0);
    __builtin_amdgcn_s_setprio(0);
    __builtin_amdgcn_sched_barrier(0);
    __builtin_amdgcn_s_barrier();
    // ================= phase 2: quadrant mh=1 =================
#pragma unroll
    for (int m = 0; m < 4; ++m)  a[m] = *(const bf16x8*)(Lb + aoff + 4096 + m * 1024);
    if (Ts < NTILES) {
      gload_lds16(pB0 + Ts * 32, ldsB + sb);
      gload_lds16(pB1 + Ts * 32, ldsB + sb + 8192);
    }
    __builtin_amdgcn_sched_barrier(0);
    __builtin_amdgcn_s_barrier();
    asm volatile("s_waitcnt lgkmcnt(0)" ::: "memory");
    __builtin_amdgcn_sched_barrier(0);
    __builtin_amdgcn_s_setprio(1);
#pragma unroll
    for (int m = 0; m < 4; ++m)
#pragma unroll
      for (int nf = 0; nf < 4; ++nf)
        acc[4 + m][nf] = __builtin_amdgcn_mfma_f32_16x16x32_bf16(a[m], b[nf], acc[4 + m][nf], 0, 0, 0);
    __builtin_amdgcn_s_setprio(0);
    __builtin_amdgcn_sched_barrier(0);
    // tile-end counted vmcnt: tiles T+2,T+3 may stay in flight; T+1 must land
    if (T < NTILES - 3)       { asm volatile("s_waitcnt vmcnt(8)" ::: "memory"); }
    else if (T == NTILES - 3) { asm volatile("s_waitcnt vmcnt(4)" ::: "memory"); }
    else if (T == NTILES - 2) { asm volatile("s_waitcnt vmcnt(0)" ::: "memory"); }
    __builtin_amdgcn_s_barrier();
  }

  // ================= epilogue =================
  if constexpr (EPI == 0) {
    const int three = tn / 3;
    const int ccb = (tn % 3) * 256;
    short* dst = (three == 0) ? o0 : (three == 1) ? o1 : o2;
    const float sc = (three == 0) ? 0.125f : 1.f;
#pragma unroll
    for (int nf = 0; nf < 4; ++nf) {
      const int cc = ccb + wn * 64 + nf * 16 + lrow;
      const int h = cc >> 6, d = cc & 63;
#pragma unroll
      for (int mf = 0; mf < 8; ++mf) {
        const int r = m0 + wm * 128 + mf * 16 + g * 4;
        const int bb = r >> 12, n = r & 4095;
        const size_t bh = (size_t)(bb * HH + h);
#pragma unroll
        for (int i = 0; i < 4; ++i)
          dst[(bh * NN + n + i) * DD + d] = (short)f2bf(acc[mf][nf][i] * sc);
      }
    }
  } else {
    // LDS-bounce: two passes of 128 rows x 256 f32 = 128 KiB each.
    float* LF = (float*)L;
#pragma unroll
    for (int pass = 0; pass < 2; ++pass) {
      if (wm == pass) {
#pragma unroll
        for (int mf = 0; mf < 8; ++mf)
#pragma unroll
          for (int nf = 0; nf < 4; ++nf)
#pragma unroll
            for (int i = 0; i < 4; ++i)
              LF[(mf * 16 + g * 4 + i) * 256 + wn * 64 + nf * 16 + lrow] = acc[mf][nf][i];
      }
      __syncthreads();
      // cooperative coalesced store: 128 rows x 64 float4 chunks
#pragma unroll
      for (int k = 0; k < 16; ++k) {
        int id = t + k * 512;
        int row = id >> 6, ch = id & 63;
        float4 v = *(const float4*)&LF[row * 256 + ch * 4];
        int R = m0 + pass * 128 + row;
        int c = n0 + ch * 4;
        int bb2 = R >> 12, n = R & 4095, h = c >> 6, d = c & 63;
        float4 bi = *(const float4*)&bias[c];
        U4 r4;
        r4.ll = *(const unsigned long long*)&o2[((size_t)(bb2 * HH + h) * NN + n) * DD + d];
        v.x += bi.x + bf2f(r4.s[0]);
        v.y += bi.y + bf2f(r4.s[1]);
        v.z += bi.z + bf2f(r4.s[2]);
        v.w += bi.w + bf2f(r4.s[3]);
        *(float4*)&fout[(size_t)R * CC + c] = v;
      }
      __syncthreads();
    }
  }
}

// ---------- landmark means (coalesced bf16x8 + shfl reduce) ----------
__global__ __launch_bounds__(64) void landmarks(
    const short* __restrict__ Qb, const short* __restrict__ Kb,
    short* __restrict__ Qlmb, short* __restrict__ Klmb,
    float* __restrict__ QlmF, float* __restrict__ KlmF) {
  int bh = blockIdx.y, l = blockIdx.x, t = threadIdx.x;
  int rg = t >> 3, dg = t & 7;
  const short* qp = Qb + ((size_t)bh * NN + l * 64 + rg) * DD + dg * 8;
  const short* kp = Kb + ((size_t)bh * NN + l * 64 + rg) * DD + dg * 8;
  float sq[8], sk[8];
#pragma unroll
  for (int j = 0; j < 8; ++j) { sq[j] = 0.f; sk[j] = 0.f; }
  for (int s = 0; s < 8; ++s) {
    bf16x8 qv = *(const bf16x8*)(qp + (size_t)s * 8 * DD);
    bf16x8 kv = *(const bf16x8*)(kp + (size_t)s * 8 * DD);
#pragma unroll
    for (int j = 0; j < 8; ++j) {
      sq[j] += bf2f((unsigned short)qv[j]);
      sk[j] += bf2f((unsigned short)kv[j]);
    }
  }
#pragma unroll
  for (int j = 0; j < 8; ++j) {
    sq[j] += __shfl_xor(sq[j], 8); sq[j] += __shfl_xor(sq[j], 16); sq[j] += __shfl_xor(sq[j], 32);
    sk[j] += __shfl_xor(sk[j], 8); sk[j] += __shfl_xor(sk[j], 16); sk[j] += __shfl_xor(sk[j], 32);
  }
  if (t < 8) {
    int o = bh * 4096 + l * 64 + dg * 8;
#pragma unroll
    for (int j = 0; j < 8; ++j) {
      float q = sq[j] * (1.f / 64.f), k = sk[j] * (1.f / 64.f);
      Qlmb[o + j] = (short)f2bf(q); Klmb[o + j] = (short)f2bf(k);
      QlmF[o + j] = q; KlmF[o + j] = k;
    }
  }
}

// ---------- kernel3 logits: S3^T = K @ Qlm^T, exp() via LDS-bounce, coalesced ----------
__global__ __launch_bounds__(256) void e1_logits(
    const short* __restrict__ Kb, const short* __restrict__ Qlmb,
    short* __restrict__ P3u, float* __restrict__ s3part) {
  int bh = blockIdx.y, n0 = blockIdx.x * 128;
  __shared__ short Qlm[64 * 72];
  __shared__ short Plds[64 * 136];
  int t = threadIdx.x;
  for (int r = 0; r < 2; r++) {
    int e = t + r * 256;
    *(bf16x8*)&Qlm[(e >> 3) * 72 + (e & 7) * 8] = *(const bf16x8*)&Qlmb[bh * 4096 + e * 8];
  }
  __syncthreads();
  int wave = t >> 6, lane = t & 63, lrow = lane & 15, g = lane >> 4, lk = g << 3;
  int nw = n0 + wave * 32;
  bf16x8 aK[2][2];
#pragma unroll
  for (int rf = 0; rf < 2; rf++)
#pragma unroll
    for (int ks = 0; ks < 2; ks++)
      aK[rf][ks] = *(const bf16x8*)&Kb[((size_t)bh * NN + nw + rf * 16 + lrow) * DD + ks * 32 + lk];
  f32x4 acc[2][4];
#pragma unroll
  for (int rf = 0; rf < 2; rf++)
#pragma unroll
    for (int lf = 0; lf < 4; lf++) acc[rf][lf] = fzero4();
#pragma unroll
  for (int ks = 0; ks < 2; ks++) {
    bf16x8 bq[4];
#pragma unroll
    for (int lf = 0; lf < 4; lf++)
      bq[lf] = *(const bf16x8*)&Qlm[(lf * 16 + lrow) * 72 + ks * 32 + lk];
#pragma unroll
    for (int rf = 0; rf < 2; rf++)
#pragma unroll
      for (int lf = 0; lf < 4; lf++)
        acc[rf][lf] = __builtin_amdgcn_mfma_f32_16x16x32_bf16(aK[rf][ks], bq[lf], acc[rf][lf], 0, 0, 0);
  }
#pragma unroll
  for (int lf = 0; lf < 4; lf++) {
    float cp = 0.f;
    int l = lf * 16 + lrow;
#pragma unroll
    for (int rf = 0; rf < 2; rf++) {
      U4 p;
#pragma unroll
      for (int i = 0; i < 4; i++) {
        float e = expf(acc[rf][lf][i]);   // logits tiny (sd~0.04): no max needed
        p.s[i] = f2bf(e); cp += e;
      }
      *(unsigned long long*)&Plds[l * 136 + wave * 32 + rf * 16 + g * 4] = p.ll;
    }
    cp += __shfl_xor(cp, 16);
    cp += __shfl_xor(cp, 32);
    if (lane < 16)
      s3part[((bh * 32 + blockIdx.x) * 4 + wave) * LL + lf * 16 + lane] = cp;
  }
  __syncthreads();
  // cooperative store: 64 rows x 16 chunks(16B) = 1024 chunks
#pragma unroll
  for (int k = 0; k < 4; ++k) {
    int id = t + k * 256;
    int row = id >> 4, ch = id & 15;
    bf16x8 v = *(const bf16x8*)&Plds[row * 136 + ch * 8];
    *(bf16x8*)&P3u[((size_t)bh * LL + row) * NN + n0 + ch * 8] = v;
  }
}

// ---------- k3V^T partials from Vb (LDS transpose): k3VTp[ch][bh][d*64+l] ----------
__global__ __launch_bounds__(256) void e2_pv(
    const short* __restrict__ Vb, const short* __restrict__ P3u,
    float* __restrict__ k3VTp) {
  int bh = blockIdx.x, chk = blockIdx.y;
  int t = threadIdx.x;
  int wave = t >> 6, lane = t & 63, lrow = lane & 15, g = lane >> 4, lk = g << 3;
  __shared__ short Vl[32 * 72];
  f32x4 acc[4];
#pragma unroll
  for (int lf = 0; lf < 4; lf++) acc[lf] = fzero4();
  const int dloc = wave * 16 + lrow;
  for (int nb = 0; nb < 16; ++nb) {
    int nbase = chk * 512 + nb * 32;
    // stage V[32n][64d] -> Vl (padded 72)
    {
      int n = t >> 3, c8 = t & 7;
      bf16x8 v = *(const bf16x8*)&Vb[((size_t)bh * NN + nbase + n) * DD + c8 * 8];
      *(bf16x8*)&Vl[n * 72 + c8 * 8] = v;
    }
    __syncthreads();
    // A-frag = V^T[d][n] via transposed scalar reads
    bf16x8 a;
#pragma unroll
    for (int j = 0; j < 8; ++j) a[j] = Vl[(lk + j) * 72 + dloc];
#pragma unroll
    for (int lf = 0; lf < 4; lf++) {
      bf16x8 b = *(const bf16x8*)&P3u[((size_t)bh * LL + lf * 16 + lrow) * NN + nbase + lk];
      acc[lf] = __builtin_amdgcn_mfma_f32_16x16x32_bf16(a, b, acc[lf], 0, 0, 0);
    }
    __syncthreads();
  }
#pragma unroll
  for (int lf = 0; lf < 4; lf++) {
    int l = lf * 16 + lrow;
#pragma unroll
    for (int i = 0; i < 4; i++) {
      int dd = wave * 16 + g * 4 + i;
      k3VTp[((size_t)chk * BH + bh) * 4096 + dd * 64 + l] = acc[lf][i];
    }
  }
}

// ---------- per-(b,h): kernel2 softmax + Newton-Schulz inverse + M = inv @ k3V ----------
__device__ __forceinline__ void mm64(const float* X, const float* Y, int row, int c0, float o[8]) {
#pragma unroll
  for (int j = 0; j < 8; j++) o[j] = 0.f;
  for (int k = 0; k < 64; k++) {
    float x = X[row * 68 + k];
    const float4* yp = (const float4*)&Y[k * 68 + c0];
    float4 y0 = yp[0], y1 = yp[1];
    o[0] += x * y0.x; o[1] += x * y0.y; o[2] += x * y0.z; o[3] += x * y0.w;
    o[4] += x * y1.x; o[5] += x * y1.y; o[6] += x * y1.z; o[7] += x * y1.w;
  }
}

__global__ __launch_bounds__(512) void newton_inv(
    const float* __restrict__ QlmF, const float* __restrict__ KlmF,
    const float* __restrict__ k3VTp, const float* __restrict__ s3part,
    short* __restrict__ MTws) {
  __shared__ float A_[64 * 68], B_[64 * 68], C_[64 * 68], D_[64 * 68], E_[64 * 68];
  __shared__ float red[64];
  __shared__ float denom_s;
  int bh = blockIdx.x, t = threadIdx.x;
  int row = t >> 3, c0 = (t & 7) << 3;
#pragma unroll
  for (int i = 0; i < 8; i++) {
    int e = t * 8 + i;
    A_[(e >> 6) * 68 + (e & 63)] = QlmF[bh * 4096 + e];
    B_[(e >> 6) * 68 + (e & 63)] = KlmF[bh * 4096 + e];
  }
  __syncthreads();
  {  // S2 = Qlm @ Klm^T ; softmax rows -> C_
    float4 ar[16];
#pragma unroll
    for (int q = 0; q < 16; q++) ar[q] = *(const float4*)&A_[row * 68 + q * 4];
    float o[8];
#pragma unroll
    for (int mm = 0; mm < 8; mm++) {
      const float4* br = (const float4*)&B_[(c0 + mm) * 68];
      float s = 0.f;
      for (int q = 0; q < 16; q++) {
        float4 b4 = br[q];
        s += ar[q].x * b4.x + ar[q].y * b4.y + ar[q].z * b4.z + ar[q].w * b4.w;
      }
      o[mm] = s;
    }
    float mx = o[0];
#pragma unroll
    for (int mm = 1; mm < 8; mm++) mx = fmaxf(mx, o[mm]);
    mx = fmaxf(mx, __shfl_xor(mx, 1));
    mx = fmaxf(mx, __shfl_xor(mx, 2));
    mx = fmaxf(mx, __shfl_xor(mx, 4));
    float ss = 0.f;
#pragma unroll
    for (int mm = 0; mm < 8; mm++) { o[mm] = expf(o[mm] - mx); ss += o[mm]; }
    ss += __shfl_xor(ss, 1); ss += __shfl_xor(ss, 2); ss += __shfl_xor(ss, 4);
    float r = 1.f / ss;
#pragma unroll
    for (int mm = 0; mm < 8; mm++) C_[row * 68 + c0 + mm] = o[mm] * r;
  }
  __syncthreads();
  if (t < 64) {
    float s = 0.f;
    for (int l2 = 0; l2 < 64; l2++) s += C_[l2 * 68 + t];
    red[t] = s;
  }
  __syncthreads();
  if (t == 0) {
    float m = red[0];
    for (int i = 1; i < 64; i++) m = fmaxf(m, red[i]);
    denom_s = m;
  }
  __syncthreads();
  {
    float rdn = 1.f / denom_s;
#pragma unroll
    for (int i = 0; i < 8; i++) D_[row * 68 + c0 + i] = C_[(c0 + i) * 68 + row] * rdn;
  }
  __syncthreads();
  float* Vc = D_;
  float* t1 = A_;
  float* t2 = B_;
  float* t3 = E_;
  float o[8];
  for (int it = 0; it < 6; it++) {
    mm64(C_, Vc, row, c0, o);                       // KV
#pragma unroll
    for (int j = 0; j < 8; j++) t1[row * 68 + c0 + j] = o[j];
    __syncthreads();
    mm64(t1, t1, row, c0, o);                       // KV@KV
#pragma unroll
    for (int j = 0; j < 8; j++) t2[row * 68 + c0 + j] = 7.f * t1[row * 68 + c0 + j] - o[j];
    __syncthreads();
    mm64(t1, t2, row, c0, o);                       // KV@(7I-KV)
#pragma unroll
    for (int j = 0; j < 8; j++) t3[row * 68 + c0 + j] = 15.f * t1[row * 68 + c0 + j] - o[j];
    __syncthreads();
    mm64(Vc, t3, row, c0, o);                       // V@(13I - T3)
#pragma unroll
    for (int j = 0; j < 8; j++) t2[row * 68 + c0 + j] = 0.25f * (13.f * Vc[row * 68 + c0 + j] - o[j]);
    __syncthreads();
    float* tmp = Vc; Vc = t2; t2 = tmp;
  }
  // reciprocal column sums of kernel3 (per landmark m)
  if (t < 64) {
    float s = 0.f;
    for (int i2 = 0; i2 < 128; i2++) s += s3part[(bh * 128 + i2) * LL + t];
    red[t] = 1.f / s;
  }
  __syncthreads();
  // stage t1[d][m] = (sum_chunks k3VTp) * (1/s_m)
#pragma unroll
  for (int i = 0; i < 8; i++) {
    int e = t * 8 + i;
    float s = 0.f;
#pragma unroll
    for (int c = 0; c < 8; c++) s += k3VTp[((size_t)c * BH + bh) * 4096 + e];
    t1[(e >> 6) * 68 + (e & 63)] = s * red[e & 63];
  }
  __syncthreads();
  {
    float4 ar[16];
#pragma unroll
    for (int q = 0; q < 16; q++) ar[q] = *(const float4*)&t1[row * 68 + q * 4];
    for (int jj = 0; jj < 8; jj++) {
      const float4* dr = (const float4*)&Vc[(c0 + jj) * 68];
      float s = 0.f;
      for (int q = 0; q < 16; q++) {
        float4 d4 = dr[q];
        s += ar[q].x * d4.x + ar[q].y * d4.y + ar[q].z * d4.z + ar[q].w * d4.w;
      }
      MTws[bh * 4096 + row * 64 + c0 + jj] = (short)f2bf(s);
    }
  }
}

// ---------- kernel1 softmax + @M  -> SV (in [B,N,C] bf16) ----------
__global__ __launch_bounds__(256) void pass2(
    const short* __restrict__ Qb, const short* __restrict__ Klmb,
    const short* __restrict__ MTws, short* __restrict__ SVb) {
  int bh = blockIdx.y, n0 = blockIdx.x * 128;
  int bb = bh / HH, hh = bh % HH;
  __shared__ short Klm[64 * 72];
  __shared__ short Mt[64 * 72];
  __shared__ short Pl[128 * 72];
  int t = threadIdx.x;
  for (int r = 0; r < 2; r++) {
    int e = t + r * 256;
    *(bf16x8*)&Klm[(e >> 3) * 72 + (e & 7) * 8] = *(const bf16x8*)&Klmb[bh * 4096 + e * 8];
    *(bf16x8*)&Mt[(e >> 3) * 72 + (e & 7) * 8]  = *(const bf16x8*)&MTws[bh * 4096 + e * 8];
  }
  __syncthreads();
  int wave = t >> 6, lane = t & 63, lrow = lane & 15, lk = (lane >> 4) << 3;
  int nw = wave * 32;
  bf16x8 aQ[2][2];
#pragma unroll
  for (int rf = 0; rf < 2; rf++)
#pragma unroll
    for (int ks = 0; ks < 2; ks++)
      aQ[rf][ks] = *(const bf16x8*)&Qb[((size_t)bh * NN + n0 + nw + rf * 16 + lrow) * DD + ks * 32 + lk];
  f32x4 s[2][4];
#pragma unroll
  for (int rf = 0; rf < 2; rf++)
#pragma unroll
    for (int jf = 0; jf < 4; jf++) s[rf][jf] = fzero4();
#pragma unroll
  for (int ks = 0; ks < 2; ks++) {
    bf16x8 bk[4];
#pragma unroll
    for (int jf = 0; jf < 4; jf++)
      bk[jf] = *(const bf16x8*)&Klm[(jf * 16 + lrow) * 72 + ks * 32 + lk];
#pragma unroll
    for (int rf = 0; rf < 2; rf++)
#pragma unroll
      for (int jf = 0; jf < 4; jf++)
        s[rf][jf] = __builtin_amdgcn_mfma_f32_16x16x32_bf16(aQ[rf][ks], bk[jf], s[rf][jf], 0, 0, 0);
  }
#pragma unroll
  for (int rf = 0; rf < 2; rf++)
#pragma unroll
    for (int i = 0; i < 4; i++) {
      float v0 = s[rf][0][i], v1 = s[rf][1][i], v2 = s[rf][2][i], v3 = s[rf][3][i];
      float mx = fmaxf(fmaxf(v0, v1), fmaxf(v2, v3));
      mx = fmaxf(mx, __shfl_xor(mx, 1));
      mx = fmaxf(mx, __shfl_xor(mx, 2));
      mx = fmaxf(mx, __shfl_xor(mx, 4));
      mx = fmaxf(mx, __shfl_xor(mx, 8));
      v0 = expf(v0 - mx); v1 = expf(v1 - mx); v2 = expf(v2 - mx); v3 = expf(v3 - mx);
      float ss = v0 + v1 + v2 + v3;
      ss += __shfl_xor(ss, 1); ss += __shfl_xor(ss, 2);
      ss += __shfl_xor(ss, 4); ss += __shfl_xor(ss, 8);
      float rr = 1.f / ss;
      int n = nw + rf * 16 + ((lane >> 4) << 2) + i;
      Pl[n * 72 + 0  + lrow] = (short)f2bf(v0 * rr);
      Pl[n * 72 + 16 + lrow] = (short)f2bf(v1 * rr);
      Pl[n * 72 + 32 + lrow] = (short)f2bf(v2 * rr);
      Pl[n * 72 + 48 + lrow] = (short)f2bf(v3 * rr);
    }
  __syncthreads();
  f32x4 o[2][4];
#pragma unroll
  for (int rf = 0; rf < 2; rf++)
#pragma unroll
    for (int df = 0; df < 4; df++) o[rf][df] = fzero4();
#pragma unroll
  for (int ks = 0; ks < 2; ks++) {
    bf16x8 aP[2];
#pragma unroll
    for (int rf = 0; rf < 2; rf++)
      aP[rf] = *(const bf16x8*)&Pl[(nw + rf * 16 + lrow) * 72 + ks * 32 + lk];
    bf16x8 bm[4];
#pragma unroll
    for (int df = 0; df < 4; df++)
      bm[df] = *(const bf16x8*)&Mt[(df * 16 + lrow) * 72 + ks * 32 + lk];
#pragma unroll
    for (int rf = 0; rf < 2; rf++)
#pragma unroll
      for (int df = 0; df < 4; df++)
        o[rf][df] = __builtin_amdgcn_mfma_f32_16x16x32_bf16(aP[rf], bm[df], o[rf][df], 0, 0, 0);
  }
#pragma unroll
  for (int rf = 0; rf < 2; rf++)
#pragma unroll
    for (int df = 0; df < 4; df++)
#pragma unroll
      for (int i = 0; i < 4; i++) {
        int n = n0 + nw + rf * 16 + ((lane >> 4) << 2) + i;
        SVb[((size_t)bb * NN + n) * CC + hh * 64 + df * 16 + lrow] = (short)f2bf(o[rf][df][i]);
      }
}

extern "C" void kernel_launch(void* const* d_in, const int* in_sizes, int n_in,
                              void* d_out, int out_size, void* d_ws, size_t ws_size,
                              hipStream_t stream) {
  const float* x      = (const float*)d_in[0];
  const float* w_qkv  = (const float*)d_in[1];
  const float* w_proj = (const float*)d_in[2];
  const float* b_proj = (const float*)d_in[3];
  float* out = (float*)d_out;

  char* p = (char*)d_ws;
  auto alloc = [&](size_t bytes) -> char* {
    char* r = p; p += (bytes + 255) & ~(size_t)255; return r;
  };
  short* xb     = (short*)alloc((size_t)MM_ * KQKV * 2);
  short* wqkvT  = (short*)alloc((size_t)NQKV * KQKV * 2);
  short* wprojT = (short*)alloc((size_t)CC * CC * 2);
  short* Qb     = (short*)alloc((size_t)BH * NN * DD * 2);
  short* Kb     = (short*)alloc((size_t)BH * NN * DD * 2);
  short* Vb     = (short*)alloc((size_t)BH * NN * DD * 2);
  short* Qlmb   = (short*)alloc((size_t)BH * LL * DD * 2);
  short* Klmb   = (short*)alloc((size_t)BH * LL * DD * 2);
  float* QlmF   = (float*)alloc((size_t)BH * LL * DD * 4);
  float* KlmF   = (float*)alloc((size_t)BH * LL * DD * 4);
  float* s3part = (float*)alloc((size_t)BH * 128 * LL * 4);
  short* P3u    = (short*)alloc((size_t)BH * LL * NN * 2);
  float* k3VTp  = (float*)alloc((size_t)8 * BH * DD * LL * 4);
  short* MTws   = (short*)alloc((size_t)BH * DD * LL * 2);
  short* SVb    = (short*)alloc((size_t)MM_ * CC * 2);

  conv_bf16<<<(MM_ * KQKV / 4 + 255) / 256, 256, 0, stream>>>(x, xb, MM_ * KQKV / 4);
  transpose_bf16<<<dim3(NQKV / 32, KQKV / 32), 256, 0, stream>>>(w_qkv, wqkvT, KQKV, NQKV);
  transpose_bf16<<<dim3(CC / 32, CC / 32), 256, 0, stream>>>(w_proj, wprojT, CC, CC);
  gemm256<0><<<dim3((MM_ / 256) * (NQKV / 256)), 512, 0, stream>>>(
      xb, wqkvT, Qb, Kb, Vb, nullptr, nullptr);
  landmarks<<<dim3(LL, BH), 64, 0, stream>>>(Qb, Kb, Qlmb, Klmb, QlmF, KlmF);
  e1_logits<<<dim3(NN / 128, BH), 256, 0, stream>>>(Kb, Qlmb, P3u, s3part);
  e2_pv<<<dim3(BH, 8), 256, 0, stream>>>(Vb, P3u, k3VTp);
  newton_inv<<<BH, 512, 0, stream>>>(QlmF, KlmF, k3VTp, s3part, MTws);
  pass2<<<dim3(NN / 128, BH), 256, 0, stream>>>(Qb, Klmb, MTws, SVb);
  gemm256<1><<<dim3((MM_ / 256) * (CC / 256)), 512, 0, stream>>>(
      SVb, wprojT, nullptr, nullptr, Vb, b_proj, out);
}

// Round 4
// 461.991 us; speedup vs baseline: 1.1615x; 1.0623x over previous
//
#include <hip/hip_runtime.h>
#include <math.h>

// ---------- problem constants ----------
#define BB   8
#define NN   4096
#define CC   768
#define HH   12
#define DD   64
#define LL   64
#define BH   96          // BB*HH
#define MM_  32768       // BB*NN
#define KQKV 768
#define NQKV 2304
#define NTILES 24        // K / 32

typedef short bf16x8 __attribute__((ext_vector_type(8)));
typedef float f32x4  __attribute__((ext_vector_type(4)));

union U4 { unsigned long long ll; unsigned short s[4]; };

__device__ __forceinline__ unsigned short f2bf(float f) {
  union { float f; unsigned u; } v; v.f = f;
  return (unsigned short)((v.u + 0x7FFFu + ((v.u >> 16) & 1u)) >> 16);
}
__device__ __forceinline__ float bf2f(unsigned short h) {
  union { unsigned u; float f; } v; v.u = ((unsigned)h) << 16;
  return v.f;
}
__device__ __forceinline__ f32x4 fzero4() {
  f32x4 z; z[0] = 0.f; z[1] = 0.f; z[2] = 0.f; z[3] = 0.f; return z;
}
__device__ __forceinline__ void gload_lds16(const void* g, void* l) {
  __builtin_amdgcn_global_load_lds(
      (const __attribute__((address_space(1))) void*)g,
      (__attribute__((address_space(3))) void*)l, 16, 0, 0);
}

// ---------- elementwise fp32 -> bf16 ----------
__global__ void conv_bf16(const float* __restrict__ in, short* __restrict__ out, int n4) {
  int i = blockIdx.x * 256 + threadIdx.x;
  if (i >= n4) return;
  float4 v = ((const float4*)in)[i];
  U4 p; p.s[0] = f2bf(v.x); p.s[1] = f2bf(v.y); p.s[2] = f2bf(v.z); p.s[3] = f2bf(v.w);
  ((unsigned long long*)out)[i] = p.ll;
}

// ---------- transpose fp32[R][C] -> bf16[C][R] ----------
__global__ __launch_bounds__(256) void transpose_bf16(
    const float* __restrict__ in, short* __restrict__ out, int R, int C) {
  __shared__ float tile[32][33];
  int c0 = blockIdx.x * 32, r0 = blockIdx.y * 32;
  int tx = threadIdx.x & 31, ty = threadIdx.x >> 5;
  for (int i = ty; i < 32; i += 8)
    tile[i][tx] = in[(r0 + i) * C + c0 + tx];
  __syncthreads();
  for (int i = ty; i < 32; i += 8)
    out[(c0 + i) * R + r0 + tx] = (short)f2bf(tile[tx][i]);
}

// ---------- 256x256 bf16 MFMA GEMM, 4-slot ring, counted vmcnt, 1 barrier/K-tile ----------
// Scheduling left to the compiler (m97-style fine lgkmcnt) + counted vmcnt ring.
// EPI 0: qkv  (A=xb,  B=wqkvT)  -> Qb (scaled 1/8), Kb, Vb (all [bh][n][d]), LDS-bounce stores
// EPI 1: proj (A=SVb, B=wprojT) -> fout = acc + bias + V-residual (Vb), LDS-bounce f32 stores
template <int EPI>
__global__ __launch_bounds__(512, 2) void gemm256(
    const short* __restrict__ A, const short* __restrict__ Bw,
    short* __restrict__ o0, short* __restrict__ o1, short* __restrict__ o2,
    const float* __restrict__ bias, float* __restrict__ fout) {
  __shared__ short L[65536];   // 128 KiB: slot s at s*32768 bytes (A 16KB | B 16KB)
  const int t = threadIdx.x;
  const int wave = t >> 6, lane = t & 63;
  const int wm = wave >> 2, wn = wave & 3;
  const int lrow = lane & 15, g = lane >> 4;

  // XCD-bijective block swizzle (gridDim.x % 8 == 0 for both uses)
  const int q8 = gridDim.x >> 3;
  const int wg = ((int)blockIdx.x & 7) * q8 + ((int)blockIdx.x >> 3);
  const int tm = wg & 127, tn = wg >> 7;
  const int m0 = tm << 8, n0 = tn << 8;

  // staging: thread stages 16B slots t*16 and t*16+8192 of each 16KB chunk.
  const int csl = (((t & 3) ^ ((t >> 3) & 3)) << 3);   // pre-swizzled source col
  const short* pA0 = A  + (size_t)(m0 + (t >> 2)) * KQKV + csl;
  const short* pA1 = pA0 + 128 * KQKV;
  const short* pB0 = Bw + (size_t)(n0 + (t >> 2)) * KQKV + csl;
  const short* pB1 = pB0 + 128 * KQKV;
  char* ldsA = (char*)L + wave * 1024;      // + slot*32768 (+8192 for rows 128..255)
  char* ldsB = ldsA + 16384;

  // fragment read addressing (swizzled): byte = r*64 + ((g ^ ((lrow>>1)&3))<<4)
  const int swz16 = ((g ^ ((lrow >> 1) & 3)) << 4);
  const int aoff = (wm * 128 + lrow) * 64 + swz16;            // + mh*4096 + m*1024
  const int boff = 16384 + (wn * 64 + lrow) * 64 + swz16;     // + nf*1024

  f32x4 acc[8][4];
#pragma unroll
  for (int i = 0; i < 8; ++i)
#pragma unroll
    for (int j = 0; j < 4; ++j) acc[i][j] = fzero4();

  // ---- prologue: stage tiles 0..2 ----
#pragma unroll
  for (int T = 0; T < 3; ++T) {
    gload_lds16(pA0 + T * 32, ldsA + T * 32768);
    gload_lds16(pA1 + T * 32, ldsA + T * 32768 + 8192);
    gload_lds16(pB0 + T * 32, ldsB + T * 32768);
    gload_lds16(pB1 + T * 32, ldsB + T * 32768 + 8192);
  }
  asm volatile("s_waitcnt vmcnt(8)" ::: "memory");
  __builtin_amdgcn_s_barrier();

  for (int T = 0; T < NTILES; ++T) {
    const char* Lb = (const char*)L + (T & 3) * 32768;
    const int Ts = T + 3;
    const int sb = (Ts & 3) * 32768;
    // stage tile T+3 into the slot freed at tile T-1's closing barrier
    if (Ts < NTILES) {
      gload_lds16(pA0 + Ts * 32, ldsA + sb);
      gload_lds16(pA1 + Ts * 32, ldsA + sb + 8192);
      gload_lds16(pB0 + Ts * 32, ldsB + sb);
      gload_lds16(pB1 + Ts * 32, ldsB + sb + 8192);
    }
    bf16x8 b[4], a0[4], a1[4];
#pragma unroll
    for (int nf = 0; nf < 4; ++nf) b[nf]  = *(const bf16x8*)(Lb + boff + nf * 1024);
#pragma unroll
    for (int m = 0; m < 4; ++m)  a0[m] = *(const bf16x8*)(Lb + aoff + m * 1024);
#pragma unroll
    for (int m = 0; m < 4; ++m)  a1[m] = *(const bf16x8*)(Lb + aoff + 4096 + m * 1024);
    __builtin_amdgcn_s_setprio(1);
#pragma unroll
    for (int m = 0; m < 4; ++m)
#pragma unroll
      for (int nf = 0; nf < 4; ++nf)
        acc[m][nf] = __builtin_amdgcn_mfma_f32_16x16x32_bf16(a0[m], b[nf], acc[m][nf], 0, 0, 0);
#pragma unroll
    for (int m = 0; m < 4; ++m)
#pragma unroll
      for (int nf = 0; nf < 4; ++nf)
        acc[4 + m][nf] = __builtin_amdgcn_mfma_f32_16x16x32_bf16(a1[m], b[nf], acc[4 + m][nf], 0, 0, 0);
    __builtin_amdgcn_s_setprio(0);
    // counted vmcnt: tile T+1 must have landed before the barrier releases readers
    if (T < NTILES - 3)       { asm volatile("s_waitcnt vmcnt(8)" ::: "memory"); }
    else if (T == NTILES - 3) { asm volatile("s_waitcnt vmcnt(4)" ::: "memory"); }
    else if (T == NTILES - 2) { asm volatile("s_waitcnt vmcnt(0)" ::: "memory"); }
    __builtin_amdgcn_s_barrier();
  }

  // ================= epilogue =================
  if constexpr (EPI == 0) {
    const int three = tn / 3;
    const int ccb = (tn % 3) * 256;
    short* dst = (three == 0) ? o0 : (three == 1) ? o1 : o2;
    const float sc = (three == 0) ? 0.125f : 1.f;
    // acc -> LDS bf16 [256][256] (exactly 128 KiB), then coalesced bf16x8 stores
    short* LS = (short*)L;
#pragma unroll
    for (int mf = 0; mf < 8; ++mf)
#pragma unroll
      for (int nf = 0; nf < 4; ++nf)
#pragma unroll
        for (int i = 0; i < 4; ++i)
          LS[(wm * 128 + mf * 16 + g * 4 + i) * 256 + wn * 64 + nf * 16 + lrow] =
              (short)f2bf(acc[mf][nf][i] * sc);
    __syncthreads();
#pragma unroll
    for (int k = 0; k < 16; ++k) {
      int id = t + k * 512;
      int row = id >> 5, ch = id & 31;
      int c = ccb + ch * 8;
      int h = c >> 6, d = c & 63;
      int r = m0 + row;
      int bb = r >> 12, n = r & 4095;
      *(bf16x8*)&dst[((size_t)(bb * HH + h) * NN + n) * DD + d] =
          *(const bf16x8*)&LS[row * 256 + ch * 8];
    }
  } else {
    // LDS-bounce: two passes of 128 rows x 256 f32 = 128 KiB each.
    float* LF = (float*)L;
#pragma unroll
    for (int pass = 0; pass < 2; ++pass) {
      if (wm == pass) {
#pragma unroll
        for (int mf = 0; mf < 8; ++mf)
#pragma unroll
          for (int nf = 0; nf < 4; ++nf)
#pragma unroll
            for (int i = 0; i < 4; ++i)
              LF[(mf * 16 + g * 4 + i) * 256 + wn * 64 + nf * 16 + lrow] = acc[mf][nf][i];
      }
      __syncthreads();
#pragma unroll
      for (int k = 0; k < 16; ++k) {
        int id = t + k * 512;
        int row = id >> 6, ch = id & 63;
        float4 v = *(const float4*)&LF[row * 256 + ch * 4];
        int R = m0 + pass * 128 + row;
        int c = n0 + ch * 4;
        int bb2 = R >> 12, n = R & 4095, h = c >> 6, d = c & 63;
        float4 bi = *(const float4*)&bias[c];
        U4 r4;
        r4.ll = *(const unsigned long long*)&o2[((size_t)(bb2 * HH + h) * NN + n) * DD + d];
        v.x += bi.x + bf2f(r4.s[0]);
        v.y += bi.y + bf2f(r4.s[1]);
        v.z += bi.z + bf2f(r4.s[2]);
        v.w += bi.w + bf2f(r4.s[3]);
        *(float4*)&fout[(size_t)R * CC + c] = v;
      }
      __syncthreads();
    }
  }
}

// ---------- landmark means (coalesced bf16x8 + shfl reduce) ----------
__global__ __launch_bounds__(64) void landmarks(
    const short* __restrict__ Qb, const short* __restrict__ Kb,
    short* __restrict__ Qlmb, short* __restrict__ Klmb,
    float* __restrict__ QlmF, float* __restrict__ KlmF) {
  int bh = blockIdx.y, l = blockIdx.x, t = threadIdx.x;
  int rg = t >> 3, dg = t & 7;
  const short* qp = Qb + ((size_t)bh * NN + l * 64 + rg) * DD + dg * 8;
  const short* kp = Kb + ((size_t)bh * NN + l * 64 + rg) * DD + dg * 8;
  float sq[8], sk[8];
#pragma unroll
  for (int j = 0; j < 8; ++j) { sq[j] = 0.f; sk[j] = 0.f; }
  for (int s = 0; s < 8; ++s) {
    bf16x8 qv = *(const bf16x8*)(qp + (size_t)s * 8 * DD);
    bf16x8 kv = *(const bf16x8*)(kp + (size_t)s * 8 * DD);
#pragma unroll
    for (int j = 0; j < 8; ++j) {
      sq[j] += bf2f((unsigned short)qv[j]);
      sk[j] += bf2f((unsigned short)kv[j]);
    }
  }
#pragma unroll
  for (int j = 0; j < 8; ++j) {
    sq[j] += __shfl_xor(sq[j], 8); sq[j] += __shfl_xor(sq[j], 16); sq[j] += __shfl_xor(sq[j], 32);
    sk[j] += __shfl_xor(sk[j], 8); sk[j] += __shfl_xor(sk[j], 16); sk[j] += __shfl_xor(sk[j], 32);
  }
  if (t < 8) {
    int o = bh * 4096 + l * 64 + dg * 8;
#pragma unroll
    for (int j = 0; j < 8; ++j) {
      float q = sq[j] * (1.f / 64.f), k = sk[j] * (1.f / 64.f);
      Qlmb[o + j] = (short)f2bf(q); Klmb[o + j] = (short)f2bf(k);
      QlmF[o + j] = q; KlmF[o + j] = k;
    }
  }
}

// ---------- fused kernel3: logits+exp (in LDS) and PV partials, no P3 round-trip ----------
// per block: n-chunk of 128 rows. Outputs: s3part partial col-sums, k3VTp[chunk][bh][d*64+l].
__global__ __launch_bounds__(256) void e12(
    const short* __restrict__ Kb, const short* __restrict__ Vb,
    const short* __restrict__ Qlmb,
    float* __restrict__ k3VTp, float* __restrict__ s3part) {
  int bh = blockIdx.y, chunk = blockIdx.x, n0 = chunk * 128;
  __shared__ short Qlm[64 * 72];
  __shared__ short Plds[64 * 136];
  __shared__ short Vl[128 * 68];
  int t = threadIdx.x;
  for (int r = 0; r < 2; r++) {
    int e = t + r * 256;
    *(bf16x8*)&Qlm[(e >> 3) * 72 + (e & 7) * 8] = *(const bf16x8*)&Qlmb[bh * 4096 + e * 8];
  }
  // stage V chunk [128][64] -> Vl [128][68] via 8B writes (alignment-safe)
#pragma unroll
  for (int r = 0; r < 4; r++) {
    int id = t + r * 256;
    int n = id >> 3, c8 = id & 7;
    U4 v;
    v.ll = *(const unsigned long long*)&Vb[((size_t)bh * NN + n0 + n) * DD + c8 * 8];
    unsigned long long v2 = *(const unsigned long long*)&Vb[((size_t)bh * NN + n0 + n) * DD + c8 * 8 + 4];
    *(unsigned long long*)&Vl[n * 68 + c8 * 8] = v.ll;
    *(unsigned long long*)&Vl[n * 68 + c8 * 8 + 4] = v2;
  }
  __syncthreads();
  int wave = t >> 6, lane = t & 63, lrow = lane & 15, g = lane >> 4, lk = g << 3;
  int nw = n0 + wave * 32;
  // ---- logits S3^T rows=n cols=l, exp -> Plds, partial col sums ----
  bf16x8 aK[2][2];
#pragma unroll
  for (int rf = 0; rf < 2; rf++)
#pragma unroll
    for (int ks = 0; ks < 2; ks++)
      aK[rf][ks] = *(const bf16x8*)&Kb[((size_t)bh * NN + nw + rf * 16 + lrow) * DD + ks * 32 + lk];
  f32x4 acc[2][4];
#pragma unroll
  for (int rf = 0; rf < 2; rf++)
#pragma unroll
    for (int lf = 0; lf < 4; lf++) acc[rf][lf] = fzero4();
#pragma unroll
  for (int ks = 0; ks < 2; ks++) {
    bf16x8 bq[4];
#pragma unroll
    for (int lf = 0; lf < 4; lf++)
      bq[lf] = *(const bf16x8*)&Qlm[(lf * 16 + lrow) * 72 + ks * 32 + lk];
#pragma unroll
    for (int rf = 0; rf < 2; rf++)
#pragma unroll
      for (int lf = 0; lf < 4; lf++)
        acc[rf][lf] = __builtin_amdgcn_mfma_f32_16x16x32_bf16(aK[rf][ks], bq[lf], acc[rf][lf], 0, 0, 0);
  }
#pragma unroll
  for (int lf = 0; lf < 4; lf++) {
    float cp = 0.f;
    int l = lf * 16 + lrow;
#pragma unroll
    for (int rf = 0; rf < 2; rf++) {
      U4 p;
#pragma unroll
      for (int i = 0; i < 4; i++) {
        float e = expf(acc[rf][lf][i]);   // logits tiny (sd~0.04): no max needed
        p.s[i] = f2bf(e); cp += e;
      }
      *(unsigned long long*)&Plds[l * 136 + wave * 32 + rf * 16 + g * 4] = p.ll;
    }
    cp += __shfl_xor(cp, 16);
    cp += __shfl_xor(cp, 32);
    if (lane < 16)
      s3part[((bh * 32 + chunk) * 4 + wave) * LL + lf * 16 + lane] = cp;
  }
  __syncthreads();
  // ---- PV: k3V^T partial [64d][64l] over this 128-n chunk ----
  f32x4 o2[4];
#pragma unroll
  for (int lf = 0; lf < 4; lf++) o2[lf] = fzero4();
  const int dloc = wave * 16 + lrow;
#pragma unroll
  for (int ks = 0; ks < 4; ++ks) {
    bf16x8 a;
#pragma unroll
    for (int j = 0; j < 8; ++j) a[j] = Vl[(ks * 32 + lk + j) * 68 + dloc];
#pragma unroll
    for (int lf = 0; lf < 4; lf++) {
      bf16x8 b = *(const bf16x8*)&Plds[(lf * 16 + lrow) * 136 + ks * 32 + lk];
      o2[lf] = __builtin_amdgcn_mfma_f32_16x16x32_bf16(a, b, o2[lf], 0, 0, 0);
    }
  }
#pragma unroll
  for (int lf = 0; lf < 4; lf++) {
    int l = lf * 16 + lrow;
#pragma unroll
    for (int i = 0; i < 4; i++) {
      int dd = wave * 16 + g * 4 + i;
      k3VTp[((size_t)chunk * BH + bh) * 4096 + dd * 64 + l] = o2[lf][i];
    }
  }
}

// ---------- per-(b,h): kernel2 softmax + Newton-Schulz inverse + M = inv @ k3V ----------
__device__ __forceinline__ void mm64(const float* X, const float* Y, int row, int c0, float o[8]) {
#pragma unroll
  for (int j = 0; j < 8; j++) o[j] = 0.f;
  for (int k = 0; k < 64; k++) {
    float x = X[row * 68 + k];
    const float4* yp = (const float4*)&Y[k * 68 + c0];
    float4 y0 = yp[0], y1 = yp[1];
    o[0] += x * y0.x; o[1] += x * y0.y; o[2] += x * y0.z; o[3] += x * y0.w;
    o[4] += x * y1.x; o[5] += x * y1.y; o[6] += x * y1.z; o[7] += x * y1.w;
  }
}

__global__ __launch_bounds__(512) void newton_inv(
    const float* __restrict__ QlmF, const float* __restrict__ KlmF,
    const float* __restrict__ k3VTp, const float* __restrict__ s3part,
    short* __restrict__ MTws) {
  __shared__ float A_[64 * 68], B_[64 * 68], C_[64 * 68], D_[64 * 68], E_[64 * 68];
  __shared__ float red[64];
  __shared__ float denom_s;
  int bh = blockIdx.x, t = threadIdx.x;
  int row = t >> 3, c0 = (t & 7) << 3;
#pragma unroll
  for (int i = 0; i < 8; i++) {
    int e = t * 8 + i;
    A_[(e >> 6) * 68 + (e & 63)] = QlmF[bh * 4096 + e];
    B_[(e >> 6) * 68 + (e & 63)] = KlmF[bh * 4096 + e];
  }
  __syncthreads();
  {  // S2 = Qlm @ Klm^T ; softmax rows -> C_
    float4 ar[16];
#pragma unroll
    for (int q = 0; q < 16; q++) ar[q] = *(const float4*)&A_[row * 68 + q * 4];
    float o[8];
#pragma unroll
    for (int mm = 0; mm < 8; mm++) {
      const float4* br = (const float4*)&B_[(c0 + mm) * 68];
      float s = 0.f;
      for (int q = 0; q < 16; q++) {
        float4 b4 = br[q];
        s += ar[q].x * b4.x + ar[q].y * b4.y + ar[q].z * b4.z + ar[q].w * b4.w;
      }
      o[mm] = s;
    }
    float mx = o[0];
#pragma unroll
    for (int mm = 1; mm < 8; mm++) mx = fmaxf(mx, o[mm]);
    mx = fmaxf(mx, __shfl_xor(mx, 1));
    mx = fmaxf(mx, __shfl_xor(mx, 2));
    mx = fmaxf(mx, __shfl_xor(mx, 4));
    float ss = 0.f;
#pragma unroll
    for (int mm = 0; mm < 8; mm++) { o[mm] = expf(o[mm] - mx); ss += o[mm]; }
    ss += __shfl_xor(ss, 1); ss += __shfl_xor(ss, 2); ss += __shfl_xor(ss, 4);
    float r = 1.f / ss;
#pragma unroll
    for (int mm = 0; mm < 8; mm++) C_[row * 68 + c0 + mm] = o[mm] * r;
  }
  __syncthreads();
  if (t < 64) {
    float s = 0.f;
    for (int l2 = 0; l2 < 64; l2++) s += C_[l2 * 68 + t];
    red[t] = s;
  }
  __syncthreads();
  if (t == 0) {
    float m = red[0];
    for (int i = 1; i < 64; i++) m = fmaxf(m, red[i]);
    denom_s = m;
  }
  __syncthreads();
  {
    float rdn = 1.f / denom_s;
#pragma unroll
    for (int i = 0; i < 8; i++) D_[row * 68 + c0 + i] = C_[(c0 + i) * 68 + row] * rdn;
  }
  __syncthreads();
  float* Vc = D_;
  float* t1 = A_;
  float* t2 = B_;
  float* t3 = E_;
  float o[8];
  for (int it = 0; it < 6; it++) {
    mm64(C_, Vc, row, c0, o);                       // KV
#pragma unroll
    for (int j = 0; j < 8; j++) t1[row * 68 + c0 + j] = o[j];
    __syncthreads();
    mm64(t1, t1, row, c0, o);                       // KV@KV
#pragma unroll
    for (int j = 0; j < 8; j++) t2[row * 68 + c0 + j] = 7.f * t1[row * 68 + c0 + j] - o[j];
    __syncthreads();
    mm64(t1, t2, row, c0, o);                       // KV@(7I-KV)
#pragma unroll
    for (int j = 0; j < 8; j++) t3[row * 68 + c0 + j] = 15.f * t1[row * 68 + c0 + j] - o[j];
    __syncthreads();
    mm64(Vc, t3, row, c0, o);                       // V@(13I - T3)
#pragma unroll
    for (int j = 0; j < 8; j++) t2[row * 68 + c0 + j] = 0.25f * (13.f * Vc[row * 68 + c0 + j] - o[j]);
    __syncthreads();
    float* tmp = Vc; Vc = t2; t2 = tmp;
  }
  // reciprocal column sums of kernel3 (per landmark m)
  if (t < 64) {
    float s = 0.f;
    for (int i2 = 0; i2 < 128; i2++) s += s3part[(bh * 128 + i2) * LL + t];
    red[t] = 1.f / s;
  }
  __syncthreads();
  // stage t1[d][m] = (sum_chunks k3VTp) * (1/s_m)
#pragma unroll
  for (int i = 0; i < 8; i++) {
    int e = t * 8 + i;
    float s = 0.f;
    for (int c = 0; c < 32; c++) s += k3VTp[((size_t)c * BH + bh) * 4096 + e];
    t1[(e >> 6) * 68 + (e & 63)] = s * red[e & 63];
  }
  __syncthreads();
  {
    float4 ar[16];
#pragma unroll
    for (int q = 0; q < 16; q++) ar[q] = *(const float4*)&t1[row * 68 + q * 4];
    for (int jj = 0; jj < 8; jj++) {
      const float4* dr = (const float4*)&Vc[(c0 + jj) * 68];
      float s = 0.f;
      for (int q = 0; q < 16; q++) {
        float4 d4 = dr[q];
        s += ar[q].x * d4.x + ar[q].y * d4.y + ar[q].z * d4.z + ar[q].w * d4.w;
      }
      MTws[bh * 4096 + row * 64 + c0 + jj] = (short)f2bf(s);
    }
  }
}

// ---------- kernel1 softmax + @M  -> SV (in [B,N,C] bf16) ----------
__global__ __launch_bounds__(256) void pass2(
    const short* __restrict__ Qb, const short* __restrict__ Klmb,
    const short* __restrict__ MTws, short* __restrict__ SVb) {
  int bh = blockIdx.y, n0 = blockIdx.x * 128;
  int bb = bh / HH, hh = bh % HH;
  __shared__ short Klm[64 * 72];
  __shared__ short Mt[64 * 72];
  __shared__ short Pl[128 * 72];
  int t = threadIdx.x;
  for (int r = 0; r < 2; r++) {
    int e = t + r * 256;
    *(bf16x8*)&Klm[(e >> 3) * 72 + (e & 7) * 8] = *(const bf16x8*)&Klmb[bh * 4096 + e * 8];
    *(bf16x8*)&Mt[(e >> 3) * 72 + (e & 7) * 8]  = *(const bf16x8*)&MTws[bh * 4096 + e * 8];
  }
  __syncthreads();
  int wave = t >> 6, lane = t & 63, lrow = lane & 15, lk = (lane >> 4) << 3;
  int nw = wave * 32;
  bf16x8 aQ[2][2];
#pragma unroll
  for (int rf = 0; rf < 2; rf++)
#pragma unroll
    for (int ks = 0; ks < 2; ks++)
      aQ[rf][ks] = *(const bf16x8*)&Qb[((size_t)bh * NN + n0 + nw + rf * 16 + lrow) * DD + ks * 32 + lk];
  f32x4 s[2][4];
#pragma unroll
  for (int rf = 0; rf < 2; rf++)
#pragma unroll
    for (int jf = 0; jf < 4; jf++) s[rf][jf] = fzero4();
#pragma unroll
  for (int ks = 0; ks < 2; ks++) {
    bf16x8 bk[4];
#pragma unroll
    for (int jf = 0; jf < 4; jf++)
      bk[jf] = *(const bf16x8*)&Klm[(jf * 16 + lrow) * 72 + ks * 32 + lk];
#pragma unroll
    for (int rf = 0; rf < 2; rf++)
#pragma unroll
      for (int jf = 0; jf < 4; jf++)
        s[rf][jf] = __builtin_amdgcn_mfma_f32_16x16x32_bf16(aQ[rf][ks], bk[jf], s[rf][jf], 0, 0, 0);
  }
#pragma unroll
  for (int rf = 0; rf < 2; rf++)
#pragma unroll
    for (int i = 0; i < 4; i++) {
      float v0 = s[rf][0][i], v1 = s[rf][1][i], v2 = s[rf][2][i], v3 = s[rf][3][i];
      float mx = fmaxf(fmaxf(v0, v1), fmaxf(v2, v3));
      mx = fmaxf(mx, __shfl_xor(mx, 1));
      mx = fmaxf(mx, __shfl_xor(mx, 2));
      mx = fmaxf(mx, __shfl_xor(mx, 4));
      mx = fmaxf(mx, __shfl_xor(mx, 8));
      v0 = expf(v0 - mx); v1 = expf(v1 - mx); v2 = expf(v2 - mx); v3 = expf(v3 - mx);
      float ss = v0 + v1 + v2 + v3;
      ss += __shfl_xor(ss, 1); ss += __shfl_xor(ss, 2);
      ss += __shfl_xor(ss, 4); ss += __shfl_xor(ss, 8);
      float rr = 1.f / ss;
      int n = nw + rf * 16 + ((lane >> 4) << 2) + i;
      Pl[n * 72 + 0  + lrow] = (short)f2bf(v0 * rr);
      Pl[n * 72 + 16 + lrow] = (short)f2bf(v1 * rr);
      Pl[n * 72 + 32 + lrow] = (short)f2bf(v2 * rr);
      Pl[n * 72 + 48 + lrow] = (short)f2bf(v3 * rr);
    }
  __syncthreads();
  f32x4 o[2][4];
#pragma unroll
  for (int rf = 0; rf < 2; rf++)
#pragma unroll
    for (int df = 0; df < 4; df++) o[rf][df] = fzero4();
#pragma unroll
  for (int ks = 0; ks < 2; ks++) {
    bf16x8 aP[2];
#pragma unroll
    for (int rf = 0; rf < 2; rf++)
      aP[rf] = *(const bf16x8*)&Pl[(nw + rf * 16 + lrow) * 72 + ks * 32 + lk];
    bf16x8 bm[4];
#pragma unroll
    for (int df = 0; df < 4; df++)
      bm[df] = *(const bf16x8*)&Mt[(df * 16 + lrow) * 72 + ks * 32 + lk];
#pragma unroll
    for (int rf = 0; rf < 2; rf++)
#pragma unroll
      for (int df = 0; df < 4; df++)
        o[rf][df] = __builtin_amdgcn_mfma_f32_16x16x32_bf16(aP[rf], bm[df], o[rf][df], 0, 0, 0);
  }
#pragma unroll
  for (int rf = 0; rf < 2; rf++)
#pragma unroll
    for (int df = 0; df < 4; df++)
#pragma unroll
      for (int i = 0; i < 4; i++) {
        int n = n0 + nw + rf * 16 + ((lane >> 4) << 2) + i;
        SVb[((size_t)bb * NN + n) * CC + hh * 64 + df * 16 + lrow] = (short)f2bf(o[rf][df][i]);
      }
}

extern "C" void kernel_launch(void* const* d_in, const int* in_sizes, int n_in,
                              void* d_out, int out_size, void* d_ws, size_t ws_size,
                              hipStream_t stream) {
  const float* x      = (const float*)d_in[0];
  const float* w_qkv  = (const float*)d_in[1];
  const float* w_proj = (const float*)d_in[2];
  const float* b_proj = (const float*)d_in[3];
  float* out = (float*)d_out;

  char* p = (char*)d_ws;
  auto alloc = [&](size_t bytes) -> char* {
    char* r = p; p += (bytes + 255) & ~(size_t)255; return r;
  };
  short* xb     = (short*)alloc((size_t)MM_ * KQKV * 2);
  short* wqkvT  = (short*)alloc((size_t)NQKV * KQKV * 2);
  short* wprojT = (short*)alloc((size_t)CC * CC * 2);
  short* Qb     = (short*)alloc((size_t)BH * NN * DD * 2);
  short* Kb     = (short*)alloc((size_t)BH * NN * DD * 2);
  short* Vb     = (short*)alloc((size_t)BH * NN * DD * 2);
  short* Qlmb   = (short*)alloc((size_t)BH * LL * DD * 2);
  short* Klmb   = (short*)alloc((size_t)BH * LL * DD * 2);
  float* QlmF   = (float*)alloc((size_t)BH * LL * DD * 4);
  float* KlmF   = (float*)alloc((size_t)BH * LL * DD * 4);
  float* s3part = (float*)alloc((size_t)BH * 128 * LL * 4);
  float* k3VTp  = (float*)alloc((size_t)32 * BH * DD * LL * 4);
  short* MTws   = (short*)alloc((size_t)BH * DD * LL * 2);
  short* SVb    = (short*)alloc((size_t)MM_ * CC * 2);

  conv_bf16<<<(MM_ * KQKV / 4 + 255) / 256, 256, 0, stream>>>(x, xb, MM_ * KQKV / 4);
  transpose_bf16<<<dim3(NQKV / 32, KQKV / 32), 256, 0, stream>>>(w_qkv, wqkvT, KQKV, NQKV);
  transpose_bf16<<<dim3(CC / 32, CC / 32), 256, 0, stream>>>(w_proj, wprojT, CC, CC);
  gemm256<0><<<dim3((MM_ / 256) * (NQKV / 256)), 512, 0, stream>>>(
      xb, wqkvT, Qb, Kb, Vb, nullptr, nullptr);
  landmarks<<<dim3(LL, BH), 64, 0, stream>>>(Qb, Kb, Qlmb, Klmb, QlmF, KlmF);
  e12<<<dim3(NN / 128, BH), 256, 0, stream>>>(Kb, Vb, Qlmb, k3VTp, s3part);
  newton_inv<<<BH, 512, 0, stream>>>(QlmF, KlmF, k3VTp, s3part, MTws);
  pass2<<<dim3(NN / 128, BH), 256, 0, stream>>>(Qb, Klmb, MTws, SVb);
  gemm256<1><<<dim3((MM_ / 256) * (CC / 256)), 512, 0, stream>>>(
      SVb, wprojT, nullptr, nullptr, Vb, b_proj, out);
}